// Round 3
// baseline (3856.093 us; speedup 1.0000x reference)
//
#include <hip/hip_runtime.h>
#include <hip/hip_bf16.h>

#define TT 2048
#define DD 1024
#define FF 2048
#define NEXPI 10   // 2 shared + 8 routed expert instances

#define BM 128
#define BN 128
#define BK 64
#define LDA 80     // padded LDS row stride in bytes (64 + 16)

typedef __attribute__((ext_vector_type(4))) int v4i;

__device__ __forceinline__ double wave_sum_d(double v) {
#pragma unroll
  for (int o = 32; o > 0; o >>= 1) v += __shfl_down(v, o);
  return v;
}
__device__ __forceinline__ double wave_max_d(double v) {
#pragma unroll
  for (int o = 32; o > 0; o >>= 1) v = fmax(v, __shfl_down(v, o));
  return v;
}

// ---------------- zero init (out + rowmax slots) ----------------
__global__ void k_zero(float* __restrict__ out, unsigned* __restrict__ rm) {
  int i = blockIdx.x * 256 + threadIdx.x;
  int stride = gridDim.x * 256;
  for (int j = i; j < TT * DD; j += stride) out[j] = 0.f;
  for (int j = i; j < NEXPI * TT; j += stride) rm[j] = 0u;
}

// ------------- rmsnorm + per-token absmax + int8 quant + bf16 h (f64 math) -------------
__global__ __launch_bounds__(256) void k_rms_quant(
    const float* __restrict__ x, const float* __restrict__ rw,
    signed char* __restrict__ qh, __hip_bfloat16* __restrict__ hb,
    double* __restrict__ amax_clip) {
  __shared__ double red[12];
  int t = blockIdx.x, tid = threadIdx.x;
  int lane = tid & 63, wid = tid >> 6;
  float4 xv = ((const float4*)(x + (size_t)t * DD))[tid];
  double x0 = xv.x, x1 = xv.y, x2 = xv.z, x3 = xv.w;
  double ss = x0 * x0 + x1 * x1 + x2 * x2 + x3 * x3;
  ss = wave_sum_d(ss);
  if (lane == 0) red[wid] = ss;
  __syncthreads();
  if (tid == 0) {
    double s = red[0] + red[1] + red[2] + red[3];
    red[8] = 1.0 / sqrt(s * (1.0 / DD) + 1e-6);
  }
  __syncthreads();
  double r = red[8];
  float4 wv = ((const float4*)rw)[tid];
  double h0 = x0 * r * (double)wv.x, h1 = x1 * r * (double)wv.y;
  double h2 = x2 * r * (double)wv.z, h3 = x3 * r * (double)wv.w;
  __hip_bfloat16* hp = hb + (size_t)t * DD + tid * 4;
  hp[0] = __float2bfloat16((float)h0); hp[1] = __float2bfloat16((float)h1);
  hp[2] = __float2bfloat16((float)h2); hp[3] = __float2bfloat16((float)h3);
  double am = fmax(fmax(fabs(h0), fabs(h1)), fmax(fabs(h2), fabs(h3)));
  am = wave_max_d(am);
  if (lane == 0) red[4 + wid] = am;
  __syncthreads();
  if (tid == 0) {
    double a = fmax(fmax(red[4], red[5]), fmax(red[6], red[7]));
    red[9] = fmax(a, 1e-5);
  }
  __syncthreads();
  double clipv = red[9];
  if (tid == 0) amax_clip[t] = clipv;
  double s = 127.0 / clipv;
  int q0 = (int)fmin(127.0, fmax(-128.0, rint(h0 * s)));
  int q1 = (int)fmin(127.0, fmax(-128.0, rint(h1 * s)));
  int q2 = (int)fmin(127.0, fmax(-128.0, rint(h2 * s)));
  int q3 = (int)fmin(127.0, fmax(-128.0, rint(h3 * s)));
  unsigned pw = (unsigned)(q0 & 255) | ((unsigned)(q1 & 255) << 8) |
                ((unsigned)(q2 & 255) << 16) | ((unsigned)(q3 & 255) << 24);
  *(unsigned*)(qh + (size_t)t * DD + tid * 4) = pw;
}

// ------------- weight absmean: f64 partial sums (20 matrices x 128 blocks) -------------
__global__ __launch_bounds__(256) void k_wabs_part(
    const float* __restrict__ w1s, const float* __restrict__ w2s,
    const float* __restrict__ w1r, const float* __restrict__ w2r,
    double* __restrict__ part) {
  __shared__ double red[4];
  int m = blockIdx.x >> 7, blk = blockIdx.x & 127;
  const float* base;
  if (m < 2)       base = w1s + (size_t)m * (DD * FF);
  else if (m < 4)  base = w2s + (size_t)(m - 2) * (DD * FF);
  else if (m < 12) base = w1r + (size_t)(m - 4) * (DD * FF);
  else             base = w2r + (size_t)(m - 12) * (DD * FF);
  const float4* p = (const float4*)(base + (size_t)blk * 16384);
  int tid = threadIdx.x;
  double s = 0.0;
#pragma unroll
  for (int i = 0; i < 16; ++i) {
    float4 v = p[tid + i * 256];
    s += (double)fabsf(v.x) + (double)fabsf(v.y) + (double)fabsf(v.z) + (double)fabsf(v.w);
  }
  s = wave_sum_d(s);
  int lane = tid & 63, wid = tid >> 6;
  if (lane == 0) red[wid] = s;
  __syncthreads();
  if (tid == 0) part[m * 128 + blk] = red[0] + red[1] + red[2] + red[3];
}

__global__ __launch_bounds__(128) void k_wscale_final(
    const double* __restrict__ part, double* __restrict__ wscale) {
  __shared__ double red[2];
  int m = blockIdx.x, tid = threadIdx.x;
  double v = part[m * 128 + tid];
  v = wave_sum_d(v);
  if ((tid & 63) == 0) red[tid >> 6] = v;
  __syncthreads();
  if (tid == 0) wscale[m] = (red[0] + red[1]) * (1.0 / 2097152.0) + 1e-8;
}

// ------------- router: bf16 products, f64 accum, **bf16-rounded logits**,
//               top-2 (lower-index tie-break), renorm -> dense gates -------------
__global__ __launch_bounds__(64) void k_router(
    const __hip_bfloat16* __restrict__ hb, const float* __restrict__ rw,
    float* __restrict__ gates) {
  int t = blockIdx.x, lane = threadIdx.x;
  double acc[8];
#pragma unroll
  for (int e = 0; e < 8; ++e) acc[e] = 0.0;
  const __hip_bfloat16* hp = hb + (size_t)t * DD;
  for (int d = lane; d < DD; d += 64) {
    double hv = (double)__bfloat162float(hp[d]);
#pragma unroll
    for (int e = 0; e < 8; ++e) {
      double wv = (double)__bfloat162float(__float2bfloat16(rw[e * DD + d]));
      acc[e] += hv * wv;
    }
  }
#pragma unroll
  for (int e = 0; e < 8; ++e) acc[e] = wave_sum_d(acc[e]);
  if (lane == 0) {
    // JAX: (bf16 @ bf16) yields a *bf16* result, then .astype(f32).
    // Round logits to bf16 — this creates exact ties that lax.top_k breaks
    // by lower index; emulate with strict-> comparisons below.
    double lb[8];
#pragma unroll
    for (int e = 0; e < 8; ++e)
      lb[e] = (double)__bfloat162float(__float2bfloat16((float)acc[e]));
    double mx = lb[0];
#pragma unroll
    for (int e = 1; e < 8; ++e) mx = fmax(mx, lb[e]);
    double p[8];
#pragma unroll
    for (int e = 0; e < 8; ++e) p[e] = exp(lb[e] - mx);
    int i0 = 0;
    for (int e = 1; e < 8; ++e) if (p[e] > p[i0]) i0 = e;
    int i1 = (i0 == 0) ? 1 : 0;
    for (int e = 0; e < 8; ++e) if (e != i0 && p[e] > p[i1]) i1 = e;
    double den = p[i0] + p[i1];
    float o[8] = {0.f, 0.f, 0.f, 0.f, 0.f, 0.f, 0.f, 0.f};
    o[i0] = (float)(p[i0] / den);
    o[i1] = (float)(p[i1] / den);
#pragma unroll
    for (int e = 0; e < 8; ++e) gates[(size_t)t * 8 + e] = o[e];
  }
}

// ------------- GEMM helpers -------------
__device__ __forceinline__ int qtern(float v, double winv) {
  double q = rint((double)v * winv);
  return (int)fmin(1.0, fmax(-1.0, q));
}

// stage B tile (BK x BN) from f32 row-major weights, ternary-quantized (f64 bins),
// TRANSPOSED into LDS as Bt[n][k] (i8, row stride LDA bytes)
__device__ __forceinline__ void stage_B(const float* __restrict__ w, int ldb,
                                        int k0, int col0, double winv,
                                        signed char* Bs, int tid) {
  int f0 = (tid & 31) * 4;
  int dg = tid >> 5;
#pragma unroll
  for (int it = 0; it < 2; ++it) {
    int dl = (dg + it * 8) * 4;
    const float* wp = w + (size_t)(k0 + dl) * ldb + col0 + f0;
    float4 r0 = *(const float4*)wp;
    float4 r1 = *(const float4*)(wp + ldb);
    float4 r2 = *(const float4*)(wp + 2 * ldb);
    float4 r3 = *(const float4*)(wp + 3 * ldb);
    int a0 = qtern(r0.x, winv), a1 = qtern(r1.x, winv), a2 = qtern(r2.x, winv), a3 = qtern(r3.x, winv);
    int b0 = qtern(r0.y, winv), b1 = qtern(r1.y, winv), b2 = qtern(r2.y, winv), b3 = qtern(r3.y, winv);
    int c0 = qtern(r0.z, winv), c1 = qtern(r1.z, winv), c2 = qtern(r2.z, winv), c3 = qtern(r3.z, winv);
    int d0 = qtern(r0.w, winv), d1 = qtern(r1.w, winv), d2 = qtern(r2.w, winv), d3 = qtern(r3.w, winv);
    *(unsigned*)(Bs + (f0 + 0) * LDA + dl) =
        (unsigned)(a0 & 255) | ((unsigned)(a1 & 255) << 8) | ((unsigned)(a2 & 255) << 16) | ((unsigned)(a3 & 255) << 24);
    *(unsigned*)(Bs + (f0 + 1) * LDA + dl) =
        (unsigned)(b0 & 255) | ((unsigned)(b1 & 255) << 8) | ((unsigned)(b2 & 255) << 16) | ((unsigned)(b3 & 255) << 24);
    *(unsigned*)(Bs + (f0 + 2) * LDA + dl) =
        (unsigned)(c0 & 255) | ((unsigned)(c1 & 255) << 8) | ((unsigned)(c2 & 255) << 16) | ((unsigned)(c3 & 255) << 24);
    *(unsigned*)(Bs + (f0 + 3) * LDA + dl) =
        (unsigned)(d0 & 255) | ((unsigned)(d1 & 255) << 8) | ((unsigned)(d2 & 255) << 16) | ((unsigned)(d3 & 255) << 24);
  }
}

__device__ __forceinline__ void mfma_tile(const signed char* As, const signed char* Bs,
                                          int lane, int wr, int wc, v4i acc[4][4]) {
  int kg = lane >> 4;
  int rsel = lane & 15;
  v4i af[4], bfr[4];
#pragma unroll
  for (int mi = 0; mi < 4; ++mi)
    af[mi] = *(const v4i*)(As + (wr * 64 + mi * 16 + rsel) * LDA + kg * 16);
#pragma unroll
  for (int ni = 0; ni < 4; ++ni)
    bfr[ni] = *(const v4i*)(Bs + (wc * 64 + ni * 16 + rsel) * LDA + kg * 16);
#pragma unroll
  for (int mi = 0; mi < 4; ++mi)
#pragma unroll
    for (int ni = 0; ni < 4; ++ni)
      acc[mi][ni] = __builtin_amdgcn_mfma_i32_16x16x64_i8(af[mi], bfr[ni], acc[mi][ni], 0, 0, 0);
}

// ------------- GEMM1: a = silu( qh(i8) @ tern(w1) ), track row absmax -------------
__global__ __launch_bounds__(256) void k_gemm1(
    const signed char* __restrict__ qh, const float* __restrict__ w,
    const double* __restrict__ wsp, const double* __restrict__ amax_clip,
    float* __restrict__ abuf, unsigned* __restrict__ rowmax) {
  __shared__ signed char As[BM * LDA];
  __shared__ signed char Bs[BN * LDA];
  int tid = threadIdx.x, lane = tid & 63, wid = tid >> 6;
  int wr = wid >> 1, wc = wid & 1;
  int row0 = blockIdx.y * BM, col0 = blockIdx.x * BN;
  double wsc = *wsp;
  double winv = 1.0 / wsc;
  v4i zero = {0, 0, 0, 0};
  v4i acc[4][4];
#pragma unroll
  for (int i = 0; i < 4; ++i)
#pragma unroll
    for (int j = 0; j < 4; ++j) acc[i][j] = zero;
  int arow = tid >> 1, ah = tid & 1;
  for (int k0 = 0; k0 < DD; k0 += BK) {
    __syncthreads();
    const int4* gp = (const int4*)(qh + (size_t)(row0 + arow) * DD + k0 + ah * 32);
    int4 v0 = gp[0], v1 = gp[1];
    *(int4*)(As + arow * LDA + ah * 32) = v0;
    *(int4*)(As + arow * LDA + ah * 32 + 16) = v1;
    stage_B(w, FF, k0, col0, winv, Bs, tid);
    __syncthreads();
    mfma_tile(As, Bs, lane, wr, wc, acc);
  }
  double csc = wsc * (1.0 / 127.0);
#pragma unroll
  for (int mi = 0; mi < 4; ++mi) {
#pragma unroll
    for (int rg = 0; rg < 4; ++rg) {
      int tr = row0 + wr * 64 + mi * 16 + ((lane >> 4) << 2) + rg;
      float sA = (float)(amax_clip[tr] * csc);
      float mloc = 0.f;
#pragma unroll
      for (int ni = 0; ni < 4; ++ni) {
        int fc = col0 + wc * 64 + ni * 16 + (lane & 15);
        float a = (float)acc[mi][ni][rg] * sA;
        float v = a / (1.f + expf(-a));
        abuf[(size_t)tr * FF + fc] = v;
        mloc = fmaxf(mloc, fabsf(v));
      }
      atomicMax(rowmax + tr, __float_as_uint(mloc));
    }
  }
}

// ------------- GEMM2: out += gate * ( q8(a) @ tern(w2) ) -------------
__global__ __launch_bounds__(256) void k_gemm2(
    const float* __restrict__ abuf, const float* __restrict__ w,
    const double* __restrict__ wsp, const unsigned* __restrict__ rowmax,
    const float* __restrict__ gates, int ei, float* __restrict__ out) {
  __shared__ signed char As[BM * LDA];
  __shared__ signed char Bs[BN * LDA];
  int tid = threadIdx.x, lane = tid & 63, wid = tid >> 6;
  int wr = wid >> 1, wc = wid & 1;
  int row0 = blockIdx.y * BM, col0 = blockIdx.x * BN;
  double wsc = *wsp;
  double winv = 1.0 / wsc;
  v4i zero = {0, 0, 0, 0};
  v4i acc[4][4];
#pragma unroll
  for (int i = 0; i < 4; ++i)
#pragma unroll
    for (int j = 0; j < 4; ++j) acc[i][j] = zero;
  int arow = tid >> 1, ah = tid & 1;
  float clipA = fmaxf(__uint_as_float(rowmax[row0 + arow]), 1e-5f);
  float sAq = 127.f / clipA;
  for (int k0 = 0; k0 < FF; k0 += BK) {
    __syncthreads();
    const float4* ap = (const float4*)(abuf + (size_t)(row0 + arow) * FF + k0 + ah * 32);
#pragma unroll
    for (int i = 0; i < 8; ++i) {
      float4 v = ap[i];
      int q0 = (int)fminf(127.f, fmaxf(-128.f, rintf(v.x * sAq)));
      int q1 = (int)fminf(127.f, fmaxf(-128.f, rintf(v.y * sAq)));
      int q2 = (int)fminf(127.f, fmaxf(-128.f, rintf(v.z * sAq)));
      int q3 = (int)fminf(127.f, fmaxf(-128.f, rintf(v.w * sAq)));
      *(unsigned*)(As + arow * LDA + ah * 32 + i * 4) =
          (unsigned)(q0 & 255) | ((unsigned)(q1 & 255) << 8) |
          ((unsigned)(q2 & 255) << 16) | ((unsigned)(q3 & 255) << 24);
    }
    stage_B(w, DD, k0, col0, winv, Bs, tid);
    __syncthreads();
    mfma_tile(As, Bs, lane, wr, wc, acc);
  }
  double csc = wsc * (1.0 / 127.0);
#pragma unroll
  for (int mi = 0; mi < 4; ++mi) {
#pragma unroll
    for (int rg = 0; rg < 4; ++rg) {
      int tr = row0 + wr * 64 + mi * 16 + ((lane >> 4) << 2) + rg;
      float clip2 = fmaxf(__uint_as_float(rowmax[tr]), 1e-5f);
      float g = gates ? gates[(size_t)tr * 8 + ei] : 1.f;
      float sc = (float)((double)clip2 * csc) * g;
#pragma unroll
      for (int ni = 0; ni < 4; ++ni) {
        int dc = col0 + wc * 64 + ni * 16 + (lane & 15);
        out[(size_t)tr * DD + dc] += (float)acc[mi][ni][rg] * sc;
      }
    }
  }
}

extern "C" void kernel_launch(void* const* d_in, const int* in_sizes, int n_in,
                              void* d_out, int out_size, void* d_ws, size_t ws_size,
                              hipStream_t stream) {
  const float* x    = (const float*)d_in[0];
  const float* rmsw = (const float*)d_in[1];
  const float* w1s  = (const float*)d_in[2];
  const float* w2s  = (const float*)d_in[3];
  const float* w1r  = (const float*)d_in[4];
  const float* w2r  = (const float*)d_in[5];
  const float* rw   = (const float*)d_in[6];
  float* out = (float*)d_out;

  char* ws = (char*)d_ws;
  // layout: qh 2MB | amax_clip (f64, 16KB) | part (f64, 20KB) | wscale (f64) |
  //         gates 64KB | rowmax 80KB | hb 4MB | abuf 16MB
  signed char* qh        = (signed char*)ws;
  double* amax_clip      = (double*)(ws + 0x200000);
  double* part           = (double*)(ws + 0x204000);
  double* wscale         = (double*)(ws + 0x209000);
  float* gates           = (float*)(ws + 0x20A000);
  unsigned* rowmax       = (unsigned*)(ws + 0x21A000);
  __hip_bfloat16* hb     = (__hip_bfloat16*)(ws + 0x22E000);
  float* abuf            = (float*)(ws + 0x62E000);

  k_zero<<<2048, 256, 0, stream>>>(out, rowmax);
  k_rms_quant<<<TT, 256, 0, stream>>>(x, rmsw, qh, hb, amax_clip);
  k_wabs_part<<<20 * 128, 256, 0, stream>>>(w1s, w2s, w1r, w2r, part);
  k_wscale_final<<<20, 128, 0, stream>>>(part, wscale);
  k_router<<<TT, 64, 0, stream>>>(hb, rw, gates);

  for (int e = 0; e < NEXPI; ++e) {
    const float* w1p;
    const float* w2p;
    int m1, m2, ei = 0;
    const float* gp;
    if (e < 2) {
      w1p = w1s + (size_t)e * DD * FF;
      w2p = w2s + (size_t)e * FF * DD;
      m1 = e; m2 = 2 + e; gp = nullptr;
    } else {
      int r = e - 2;
      w1p = w1r + (size_t)r * DD * FF;
      w2p = w2r + (size_t)r * FF * DD;
      m1 = 4 + r; m2 = 12 + r; gp = gates; ei = r;
    }
    dim3 g1(FF / BN, TT / BM);
    k_gemm1<<<g1, 256, 0, stream>>>(qh, w1p, wscale + m1, amax_clip, abuf,
                                    rowmax + (size_t)e * TT);
    dim3 g2(DD / BN, TT / BM);
    k_gemm2<<<g2, 256, 0, stream>>>(abuf, w2p, wscale + m2,
                                    rowmax + (size_t)e * TT, gp, ei, out);
  }
}

// Round 4
// 631.978 us; speedup vs baseline: 6.1016x; 6.1016x over previous
//
#include <hip/hip_runtime.h>
#include <hip/hip_bf16.h>

#define TT 2048
#define DD 1024
#define FF 2048
#define NEXPI 10   // 2 shared + 8 routed expert instances

#define LDA 80     // padded LDS row stride in bytes (64 + 16)

typedef __attribute__((ext_vector_type(4))) int v4i;

__device__ __forceinline__ double wave_sum_d(double v) {
#pragma unroll
  for (int o = 32; o > 0; o >>= 1) v += __shfl_down(v, o);
  return v;
}
__device__ __forceinline__ double wave_max_d(double v) {
#pragma unroll
  for (int o = 32; o > 0; o >>= 1) v = fmax(v, __shfl_down(v, o));
  return v;
}

// ---------------- zero init (out + rowmax slots) ----------------
__global__ void k_zero(float* __restrict__ out, unsigned* __restrict__ rm) {
  int i = blockIdx.x * 256 + threadIdx.x;
  int stride = gridDim.x * 256;
  for (int j = i; j < TT * DD; j += stride) out[j] = 0.f;
  for (int j = i; j < NEXPI * TT; j += stride) rm[j] = 0u;
}

// ------------- rmsnorm + per-token absmax + int8 quant + bf16 h (f64 math) -------------
__global__ __launch_bounds__(256) void k_rms_quant(
    const float* __restrict__ x, const float* __restrict__ rw,
    signed char* __restrict__ qh, __hip_bfloat16* __restrict__ hb,
    double* __restrict__ amax_clip) {
  __shared__ double red[12];
  int t = blockIdx.x, tid = threadIdx.x;
  int lane = tid & 63, wid = tid >> 6;
  float4 xv = ((const float4*)(x + (size_t)t * DD))[tid];
  double x0 = xv.x, x1 = xv.y, x2 = xv.z, x3 = xv.w;
  double ss = x0 * x0 + x1 * x1 + x2 * x2 + x3 * x3;
  ss = wave_sum_d(ss);
  if (lane == 0) red[wid] = ss;
  __syncthreads();
  if (tid == 0) {
    double s = red[0] + red[1] + red[2] + red[3];
    red[8] = 1.0 / sqrt(s * (1.0 / DD) + 1e-6);
  }
  __syncthreads();
  double r = red[8];
  float4 wv = ((const float4*)rw)[tid];
  double h0 = x0 * r * (double)wv.x, h1 = x1 * r * (double)wv.y;
  double h2 = x2 * r * (double)wv.z, h3 = x3 * r * (double)wv.w;
  __hip_bfloat16* hp = hb + (size_t)t * DD + tid * 4;
  hp[0] = __float2bfloat16((float)h0); hp[1] = __float2bfloat16((float)h1);
  hp[2] = __float2bfloat16((float)h2); hp[3] = __float2bfloat16((float)h3);
  double am = fmax(fmax(fabs(h0), fabs(h1)), fmax(fabs(h2), fabs(h3)));
  am = wave_max_d(am);
  if (lane == 0) red[4 + wid] = am;
  __syncthreads();
  if (tid == 0) {
    double a = fmax(fmax(red[4], red[5]), fmax(red[6], red[7]));
    red[9] = fmax(a, 1e-5);
  }
  __syncthreads();
  double clipv = red[9];
  if (tid == 0) amax_clip[t] = clipv;
  double s = 127.0 / clipv;
  int q0 = (int)fmin(127.0, fmax(-128.0, rint(h0 * s)));
  int q1 = (int)fmin(127.0, fmax(-128.0, rint(h1 * s)));
  int q2 = (int)fmin(127.0, fmax(-128.0, rint(h2 * s)));
  int q3 = (int)fmin(127.0, fmax(-128.0, rint(h3 * s)));
  unsigned pw = (unsigned)(q0 & 255) | ((unsigned)(q1 & 255) << 8) |
                ((unsigned)(q2 & 255) << 16) | ((unsigned)(q3 & 255) << 24);
  *(unsigned*)(qh + (size_t)t * DD + tid * 4) = pw;
}

// ------------- weight absmean: f64 partial sums (20 matrices x 128 blocks) -------------
__global__ __launch_bounds__(256) void k_wabs_part(
    const float* __restrict__ w1s, const float* __restrict__ w2s,
    const float* __restrict__ w1r, const float* __restrict__ w2r,
    double* __restrict__ part) {
  __shared__ double red[4];
  int m = blockIdx.x >> 7, blk = blockIdx.x & 127;
  const float* base;
  if (m < 2)       base = w1s + (size_t)m * (DD * FF);
  else if (m < 4)  base = w2s + (size_t)(m - 2) * (DD * FF);
  else if (m < 12) base = w1r + (size_t)(m - 4) * (DD * FF);
  else             base = w2r + (size_t)(m - 12) * (DD * FF);
  const float4* p = (const float4*)(base + (size_t)blk * 16384);
  int tid = threadIdx.x;
  double s = 0.0;
#pragma unroll
  for (int i = 0; i < 16; ++i) {
    float4 v = p[tid + i * 256];
    s += (double)fabsf(v.x) + (double)fabsf(v.y) + (double)fabsf(v.z) + (double)fabsf(v.w);
  }
  s = wave_sum_d(s);
  int lane = tid & 63, wid = tid >> 6;
  if (lane == 0) red[wid] = s;
  __syncthreads();
  if (tid == 0) part[m * 128 + blk] = red[0] + red[1] + red[2] + red[3];
}

__global__ __launch_bounds__(128) void k_wscale_final(
    const double* __restrict__ part, double* __restrict__ wscale) {
  __shared__ double red[2];
  int m = blockIdx.x, tid = threadIdx.x;
  double v = part[m * 128 + tid];
  v = wave_sum_d(v);
  if ((tid & 63) == 0) red[tid >> 6] = v;
  __syncthreads();
  if (tid == 0) wscale[m] = (red[0] + red[1]) * (1.0 / 2097152.0) + 1e-8;
}

// ------------- router: bf16 products, f64 accum, bf16-rounded logits,
//               top-2 (lower-index tie-break), renorm -> dense gates -------------
__global__ __launch_bounds__(64) void k_router(
    const __hip_bfloat16* __restrict__ hb, const float* __restrict__ rw,
    float* __restrict__ gates) {
  int t = blockIdx.x, lane = threadIdx.x;
  double acc[8];
#pragma unroll
  for (int e = 0; e < 8; ++e) acc[e] = 0.0;
  const __hip_bfloat16* hp = hb + (size_t)t * DD;
  for (int d = lane; d < DD; d += 64) {
    double hv = (double)__bfloat162float(hp[d]);
#pragma unroll
    for (int e = 0; e < 8; ++e) {
      double wv = (double)__bfloat162float(__float2bfloat16(rw[e * DD + d]));
      acc[e] += hv * wv;
    }
  }
#pragma unroll
  for (int e = 0; e < 8; ++e) acc[e] = wave_sum_d(acc[e]);
  if (lane == 0) {
    double lb[8];
#pragma unroll
    for (int e = 0; e < 8; ++e)
      lb[e] = (double)__bfloat162float(__float2bfloat16((float)acc[e]));
    double mx = lb[0];
#pragma unroll
    for (int e = 1; e < 8; ++e) mx = fmax(mx, lb[e]);
    double p[8];
#pragma unroll
    for (int e = 0; e < 8; ++e) p[e] = exp(lb[e] - mx);
    int i0 = 0;
    for (int e = 1; e < 8; ++e) if (p[e] > p[i0]) i0 = e;
    int i1 = (i0 == 0) ? 1 : 0;
    for (int e = 0; e < 8; ++e) if (e != i0 && p[e] > p[i1]) i1 = e;
    double den = p[i0] + p[i1];
    float o[8] = {0.f, 0.f, 0.f, 0.f, 0.f, 0.f, 0.f, 0.f};
    o[i0] = (float)(p[i0] / den);
    o[i1] = (float)(p[i1] / den);
#pragma unroll
    for (int e = 0; e < 8; ++e) gates[(size_t)t * 8 + e] = o[e];
  }
}

// ------------- ternary quant helper (f64 bins, bit-identical to reference) -------------
__device__ __forceinline__ int qtern(float v, double winv) {
  double q = rint((double)v * winv);
  return (int)fmin(1.0, fmax(-1.0, q));
}
__device__ __forceinline__ unsigned pack4(int a, int b, int c, int d) {
  return (unsigned)(a & 255) | ((unsigned)(b & 255) << 8) |
         ((unsigned)(c & 255) << 16) | ((unsigned)(d & 255) << 24);
}

// ------------- weight quant + transpose: f32 [R][C] -> i8 W^T [C][R] -------------
// 20 matrices x 512 tiles of 64x64. m: 0,1=w1s 2,3=w2s 4..11=w1r 12..19=w2r
__global__ __launch_bounds__(256) void k_wquant(
    const float* __restrict__ w1s, const float* __restrict__ w2s,
    const float* __restrict__ w1r, const float* __restrict__ w2r,
    const double* __restrict__ wscale,
    signed char* __restrict__ q1T, signed char* __restrict__ q2T) {
  __shared__ signed char tile[64 * 68];
  int bid = blockIdx.x;
  int m = bid >> 9, t = bid & 511;
  const float* src;
  signed char* dst;
  int ld, ldo, rt, ct;
  if (m < 2) {        // w1 shared: [DD][FF] -> q1T slot m
    src = w1s + (size_t)m * DD * FF;
    dst = q1T + (size_t)m * FF * DD;
    ld = FF; ldo = DD; rt = t >> 5; ct = t & 31;
  } else if (m < 4) { // w2 shared: [FF][DD] -> q2T slot m-2
    src = w2s + (size_t)(m - 2) * FF * DD;
    dst = q2T + (size_t)(m - 2) * DD * FF;
    ld = DD; ldo = FF; rt = t >> 4; ct = t & 15;
  } else if (m < 12) { // w1 routed: slot m-2 (2..9)
    src = w1r + (size_t)(m - 4) * DD * FF;
    dst = q1T + (size_t)(m - 2) * FF * DD;
    ld = FF; ldo = DD; rt = t >> 5; ct = t & 31;
  } else {             // w2 routed: slot m-10 (2..9)
    src = w2r + (size_t)(m - 12) * FF * DD;
    dst = q2T + (size_t)(m - 10) * DD * FF;
    ld = DD; ldo = FF; rt = t >> 4; ct = t & 15;
  }
  double winv = 1.0 / wscale[m];
  int row0 = rt * 64, col0 = ct * 64;
  int r = threadIdx.x >> 2, sc_ = (threadIdx.x & 3) * 16;
  const float* sp = src + (size_t)(row0 + r) * ld + col0 + sc_;
#pragma unroll
  for (int g = 0; g < 4; ++g) {
    float4 v = *(const float4*)(sp + g * 4);
    unsigned pk = pack4(qtern(v.x, winv), qtern(v.y, winv),
                        qtern(v.z, winv), qtern(v.w, winv));
    *(unsigned*)(tile + r * 68 + sc_ + g * 4) = pk;
  }
  __syncthreads();
  int c = threadIdx.x >> 2, sr = (threadIdx.x & 3) * 16;
  unsigned o[4];
#pragma unroll
  for (int g = 0; g < 4; ++g) {
    int j = sr + g * 4;
    o[g] = pack4(tile[(j + 0) * 68 + c], tile[(j + 1) * 68 + c],
                 tile[(j + 2) * 68 + c], tile[(j + 3) * 68 + c]);
  }
  int4 ov = make_int4((int)o[0], (int)o[1], (int)o[2], (int)o[3]);
  *(int4*)(dst + (size_t)(col0 + c) * ldo + row0 + sr) = ov;
}

// ------------- 64x64 MFMA tile (4 waves, 2x2 wave grid, 32x32 per wave) -------------
__device__ __forceinline__ void mfma_tile64(const signed char* As, const signed char* Bs,
                                            int lane, int wr, int wc, v4i acc[2][2]) {
  int kg = lane >> 4, rsel = lane & 15;
  v4i af[2], bf[2];
#pragma unroll
  for (int mi = 0; mi < 2; ++mi)
    af[mi] = *(const v4i*)(As + (wr * 32 + mi * 16 + rsel) * LDA + kg * 16);
#pragma unroll
  for (int ni = 0; ni < 2; ++ni)
    bf[ni] = *(const v4i*)(Bs + (wc * 32 + ni * 16 + rsel) * LDA + kg * 16);
#pragma unroll
  for (int mi = 0; mi < 2; ++mi)
#pragma unroll
    for (int ni = 0; ni < 2; ++ni)
      acc[mi][ni] = __builtin_amdgcn_mfma_i32_16x16x64_i8(af[mi], bf[ni], acc[mi][ni], 0, 0, 0);
}

// ------------- GEMM1: a = silu( qh(i8) @ q1T^T ), track row absmax -------------
// grid: (FF/64, TT/64)
__global__ __launch_bounds__(256) void k_gemm1(
    const signed char* __restrict__ qh, const signed char* __restrict__ qw,
    const double* __restrict__ wsp, const double* __restrict__ amax_clip,
    float* __restrict__ abuf, unsigned* __restrict__ rowmax) {
  __shared__ signed char As[64 * LDA];
  __shared__ signed char Bs[64 * LDA];
  int tid = threadIdx.x, lane = tid & 63, wid = tid >> 6;
  int wr = wid >> 1, wc = wid & 1;
  int row0 = blockIdx.y * 64, col0 = blockIdx.x * 64;
  double wsc = *wsp;
  v4i zero = {0, 0, 0, 0};
  v4i acc[2][2] = {{zero, zero}, {zero, zero}};
  int arow = tid >> 2, aseg = (tid & 3) * 16;
  const signed char* ap = qh + (size_t)(row0 + arow) * DD + aseg;
  const signed char* bp = qw + (size_t)(col0 + arow) * DD + aseg;
  for (int k0 = 0; k0 < DD; k0 += 64) {
    __syncthreads();
    int4 va = *(const int4*)(ap + k0);
    int4 vb = *(const int4*)(bp + k0);
    *(int4*)(As + arow * LDA + aseg) = va;
    *(int4*)(Bs + arow * LDA + aseg) = vb;
    __syncthreads();
    mfma_tile64(As, Bs, lane, wr, wc, acc);
  }
  double csc = wsc * (1.0 / 127.0);
#pragma unroll
  for (int mi = 0; mi < 2; ++mi) {
#pragma unroll
    for (int rg = 0; rg < 4; ++rg) {
      int tr = row0 + wr * 32 + mi * 16 + ((lane >> 4) << 2) + rg;
      float sA = (float)(amax_clip[tr] * csc);
      float mloc = 0.f;
#pragma unroll
      for (int ni = 0; ni < 2; ++ni) {
        int fc = col0 + wc * 32 + ni * 16 + (lane & 15);
        float a = (float)acc[mi][ni][rg] * sA;
        float v = a / (1.f + expf(-a));
        abuf[(size_t)tr * FF + fc] = v;
        mloc = fmaxf(mloc, fabsf(v));
      }
#pragma unroll
      for (int o = 1; o < 16; o <<= 1) mloc = fmaxf(mloc, __shfl_xor(mloc, o));
      if ((lane & 15) == 0) atomicMax(rowmax + tr, __float_as_uint(mloc));
    }
  }
}

// ------------- GEMM2: out += gate * ( q8(a) @ q2T^T ) -------------
// grid: (DD/64, TT/64)
__global__ __launch_bounds__(256) void k_gemm2(
    const float* __restrict__ abuf, const signed char* __restrict__ qw,
    const double* __restrict__ wsp, const unsigned* __restrict__ rowmax,
    const float* __restrict__ gates, int ei, float* __restrict__ out) {
  __shared__ signed char As[64 * LDA];
  __shared__ signed char Bs[64 * LDA];
  int tid = threadIdx.x, lane = tid & 63, wid = tid >> 6;
  int wr = wid >> 1, wc = wid & 1;
  int row0 = blockIdx.y * 64, col0 = blockIdx.x * 64;
  double wsc = *wsp;
  v4i zero = {0, 0, 0, 0};
  v4i acc[2][2] = {{zero, zero}, {zero, zero}};
  int arow = tid >> 2, aseg = (tid & 3) * 16;
  float clipA = fmaxf(__uint_as_float(rowmax[row0 + arow]), 1e-5f);
  float sAq = 127.f / clipA;
  const float* ap = abuf + (size_t)(row0 + arow) * FF + aseg;
  const signed char* bp = qw + (size_t)(col0 + arow) * FF + aseg;
  for (int k0 = 0; k0 < FF; k0 += 64) {
    __syncthreads();
    unsigned pk[4];
#pragma unroll
    for (int g = 0; g < 4; ++g) {
      float4 v = *(const float4*)(ap + k0 + g * 4);
      int q0 = (int)fminf(127.f, fmaxf(-128.f, rintf(v.x * sAq)));
      int q1 = (int)fminf(127.f, fmaxf(-128.f, rintf(v.y * sAq)));
      int q2 = (int)fminf(127.f, fmaxf(-128.f, rintf(v.z * sAq)));
      int q3 = (int)fminf(127.f, fmaxf(-128.f, rintf(v.w * sAq)));
      pk[g] = pack4(q0, q1, q2, q3);
    }
    int4 vb = *(const int4*)(bp + k0);
    int4 va = make_int4((int)pk[0], (int)pk[1], (int)pk[2], (int)pk[3]);
    *(int4*)(As + arow * LDA + aseg) = va;
    *(int4*)(Bs + arow * LDA + aseg) = vb;
    __syncthreads();
    mfma_tile64(As, Bs, lane, wr, wc, acc);
  }
  double csc = wsc * (1.0 / 127.0);
#pragma unroll
  for (int mi = 0; mi < 2; ++mi) {
#pragma unroll
    for (int rg = 0; rg < 4; ++rg) {
      int tr = row0 + wr * 32 + mi * 16 + ((lane >> 4) << 2) + rg;
      float clip2 = fmaxf(__uint_as_float(rowmax[tr]), 1e-5f);
      float g = gates ? gates[(size_t)tr * 8 + ei] : 1.f;
      float sc = (float)((double)clip2 * csc) * g;
#pragma unroll
      for (int ni = 0; ni < 2; ++ni) {
        int dc = col0 + wc * 32 + ni * 16 + (lane & 15);
        out[(size_t)tr * DD + dc] += (float)acc[mi][ni][rg] * sc;
      }
    }
  }
}

extern "C" void kernel_launch(void* const* d_in, const int* in_sizes, int n_in,
                              void* d_out, int out_size, void* d_ws, size_t ws_size,
                              hipStream_t stream) {
  const float* x    = (const float*)d_in[0];
  const float* rmsw = (const float*)d_in[1];
  const float* w1s  = (const float*)d_in[2];
  const float* w2s  = (const float*)d_in[3];
  const float* w1r  = (const float*)d_in[4];
  const float* w2r  = (const float*)d_in[5];
  const float* rw   = (const float*)d_in[6];
  float* out = (float*)d_out;

  char* ws = (char*)d_ws;
  // qh 2MB | amax_clip f64 16KB | part f64 20KB | wscale f64 | gates 64KB |
  // rowmax 80KB | hb 4MB | q1T 20MB | q2T 20MB | abuf 16.8MB   (~66MB total)
  signed char* qh        = (signed char*)ws;
  double* amax_clip      = (double*)(ws + 0x200000);
  double* part           = (double*)(ws + 0x204000);
  double* wscale         = (double*)(ws + 0x209000);
  float* gates           = (float*)(ws + 0x20A000);
  unsigned* rowmax       = (unsigned*)(ws + 0x21A000);
  __hip_bfloat16* hb     = (__hip_bfloat16*)(ws + 0x22E000);
  signed char* q1T       = (signed char*)(ws + 0x62E000);
  signed char* q2T       = (signed char*)(ws + 0x1A2E000);
  float* abuf            = (float*)(ws + 0x2E2E000);

  k_zero<<<2048, 256, 0, stream>>>(out, rowmax);
  k_rms_quant<<<TT, 256, 0, stream>>>(x, rmsw, qh, hb, amax_clip);
  k_wabs_part<<<20 * 128, 256, 0, stream>>>(w1s, w2s, w1r, w2r, part);
  k_wscale_final<<<20, 128, 0, stream>>>(part, wscale);
  k_router<<<TT, 64, 0, stream>>>(hb, rw, gates);
  k_wquant<<<20 * 512, 256, 0, stream>>>(w1s, w2s, w1r, w2r, wscale, q1T, q2T);

  for (int e = 0; e < NEXPI; ++e) {
    int m1, m2, ei = 0;
    const float* gp;
    if (e < 2) { m1 = e; m2 = 2 + e; gp = nullptr; }
    else       { int r = e - 2; m1 = 4 + r; m2 = 12 + r; gp = gates; ei = r; }
    const signed char* q1p = q1T + (size_t)e * FF * DD;
    const signed char* q2p = q2T + (size_t)e * DD * FF;
    dim3 g1(FF / 64, TT / 64);
    k_gemm1<<<g1, 256, 0, stream>>>(qh, q1p, wscale + m1, amax_clip, abuf,
                                    rowmax + (size_t)e * TT);
    dim3 g2(DD / 64, TT / 64);
    k_gemm2<<<g2, 256, 0, stream>>>(abuf, q2p, wscale + m2,
                                    rowmax + (size_t)e * TT, gp, ei, out);
  }
}

// Round 5
// 445.175 us; speedup vs baseline: 8.6620x; 1.4196x over previous
//
#include <hip/hip_runtime.h>
#include <hip/hip_bf16.h>

#define TT 2048
#define DD 1024
#define FF 2048
#define NEXPI 10   // 2 shared + 8 routed expert instances

#define LDA 80     // padded LDS row stride in bytes (64 + 16)

typedef __attribute__((ext_vector_type(4))) int v4i;

__device__ __forceinline__ double wave_sum_d(double v) {
#pragma unroll
  for (int o = 32; o > 0; o >>= 1) v += __shfl_down(v, o);
  return v;
}
__device__ __forceinline__ double wave_max_d(double v) {
#pragma unroll
  for (int o = 32; o > 0; o >>= 1) v = fmax(v, __shfl_down(v, o));
  return v;
}

// ---------------- zero init (rowmax slots only; out is fully written by gemm2) ----------------
__global__ void k_zero(unsigned* __restrict__ rm) {
  int i = blockIdx.x * 256 + threadIdx.x;
  if (i < NEXPI * TT) rm[i] = 0u;
}

// ------------- rmsnorm + per-token absmax + int8 quant + bf16 h (f64 math) -------------
__global__ __launch_bounds__(256) void k_rms_quant(
    const float* __restrict__ x, const float* __restrict__ rw,
    signed char* __restrict__ qh, __hip_bfloat16* __restrict__ hb,
    double* __restrict__ amax_clip) {
  __shared__ double red[12];
  int t = blockIdx.x, tid = threadIdx.x;
  int lane = tid & 63, wid = tid >> 6;
  float4 xv = ((const float4*)(x + (size_t)t * DD))[tid];
  double x0 = xv.x, x1 = xv.y, x2 = xv.z, x3 = xv.w;
  double ss = x0 * x0 + x1 * x1 + x2 * x2 + x3 * x3;
  ss = wave_sum_d(ss);
  if (lane == 0) red[wid] = ss;
  __syncthreads();
  if (tid == 0) {
    double s = red[0] + red[1] + red[2] + red[3];
    red[8] = 1.0 / sqrt(s * (1.0 / DD) + 1e-6);
  }
  __syncthreads();
  double r = red[8];
  float4 wv = ((const float4*)rw)[tid];
  double h0 = x0 * r * (double)wv.x, h1 = x1 * r * (double)wv.y;
  double h2 = x2 * r * (double)wv.z, h3 = x3 * r * (double)wv.w;
  __hip_bfloat16* hp = hb + (size_t)t * DD + tid * 4;
  hp[0] = __float2bfloat16((float)h0); hp[1] = __float2bfloat16((float)h1);
  hp[2] = __float2bfloat16((float)h2); hp[3] = __float2bfloat16((float)h3);
  double am = fmax(fmax(fabs(h0), fabs(h1)), fmax(fabs(h2), fabs(h3)));
  am = wave_max_d(am);
  if (lane == 0) red[4 + wid] = am;
  __syncthreads();
  if (tid == 0) {
    double a = fmax(fmax(red[4], red[5]), fmax(red[6], red[7]));
    red[9] = fmax(a, 1e-5);
  }
  __syncthreads();
  double clipv = red[9];
  if (tid == 0) amax_clip[t] = clipv;
  double s = 127.0 / clipv;
  int q0 = (int)fmin(127.0, fmax(-128.0, rint(h0 * s)));
  int q1 = (int)fmin(127.0, fmax(-128.0, rint(h1 * s)));
  int q2 = (int)fmin(127.0, fmax(-128.0, rint(h2 * s)));
  int q3 = (int)fmin(127.0, fmax(-128.0, rint(h3 * s)));
  unsigned pw = (unsigned)(q0 & 255) | ((unsigned)(q1 & 255) << 8) |
                ((unsigned)(q2 & 255) << 16) | ((unsigned)(q3 & 255) << 24);
  *(unsigned*)(qh + (size_t)t * DD + tid * 4) = pw;
}

// ------------- weight absmean: f64 partial sums, 4-way ILP -------------
__global__ __launch_bounds__(256) void k_wabs_part(
    const float* __restrict__ w1s, const float* __restrict__ w2s,
    const float* __restrict__ w1r, const float* __restrict__ w2r,
    double* __restrict__ part) {
  __shared__ double red[4];
  int m = blockIdx.x >> 7, blk = blockIdx.x & 127;
  const float* base;
  if (m < 2)       base = w1s + (size_t)m * (DD * FF);
  else if (m < 4)  base = w2s + (size_t)(m - 2) * (DD * FF);
  else if (m < 12) base = w1r + (size_t)(m - 4) * (DD * FF);
  else             base = w2r + (size_t)(m - 12) * (DD * FF);
  const float4* p = (const float4*)(base + (size_t)blk * 16384);
  int tid = threadIdx.x;
  double s0 = 0.0, s1 = 0.0, s2 = 0.0, s3 = 0.0;
#pragma unroll
  for (int i = 0; i < 4; ++i) {
    float4 va = p[tid + (i * 4 + 0) * 256];
    float4 vb = p[tid + (i * 4 + 1) * 256];
    float4 vc = p[tid + (i * 4 + 2) * 256];
    float4 vd = p[tid + (i * 4 + 3) * 256];
    s0 += (double)fabsf(va.x) + (double)fabsf(va.y) + (double)fabsf(va.z) + (double)fabsf(va.w);
    s1 += (double)fabsf(vb.x) + (double)fabsf(vb.y) + (double)fabsf(vb.z) + (double)fabsf(vb.w);
    s2 += (double)fabsf(vc.x) + (double)fabsf(vc.y) + (double)fabsf(vc.z) + (double)fabsf(vc.w);
    s3 += (double)fabsf(vd.x) + (double)fabsf(vd.y) + (double)fabsf(vd.z) + (double)fabsf(vd.w);
  }
  double s = (s0 + s1) + (s2 + s3);
  s = wave_sum_d(s);
  int lane = tid & 63, wid = tid >> 6;
  if (lane == 0) red[wid] = s;
  __syncthreads();
  if (tid == 0) part[m * 128 + blk] = red[0] + red[1] + red[2] + red[3];
}

__global__ __launch_bounds__(128) void k_wscale_final(
    const double* __restrict__ part, double* __restrict__ wscale) {
  __shared__ double red[2];
  int m = blockIdx.x, tid = threadIdx.x;
  double v = part[m * 128 + tid];
  v = wave_sum_d(v);
  if ((tid & 63) == 0) red[tid >> 6] = v;
  __syncthreads();
  if (tid == 0) wscale[m] = (red[0] + red[1]) * (1.0 / 2097152.0) + 1e-8;
}

// ------------- router: bf16 products, f64 accum, bf16-rounded logits,
//               top-2 (lower-index tie-break), renorm -> dense gates -------------
__global__ __launch_bounds__(64) void k_router(
    const __hip_bfloat16* __restrict__ hb, const float* __restrict__ rw,
    float* __restrict__ gates) {
  int t = blockIdx.x, lane = threadIdx.x;
  double acc[8];
#pragma unroll
  for (int e = 0; e < 8; ++e) acc[e] = 0.0;
  const __hip_bfloat16* hp = hb + (size_t)t * DD;
  for (int d = lane; d < DD; d += 64) {
    double hv = (double)__bfloat162float(hp[d]);
#pragma unroll
    for (int e = 0; e < 8; ++e) {
      double wv = (double)__bfloat162float(__float2bfloat16(rw[e * DD + d]));
      acc[e] += hv * wv;
    }
  }
#pragma unroll
  for (int e = 0; e < 8; ++e) acc[e] = wave_sum_d(acc[e]);
  if (lane == 0) {
    double lb[8];
#pragma unroll
    for (int e = 0; e < 8; ++e)
      lb[e] = (double)__bfloat162float(__float2bfloat16((float)acc[e]));
    double mx = lb[0];
#pragma unroll
    for (int e = 1; e < 8; ++e) mx = fmax(mx, lb[e]);
    double p[8];
#pragma unroll
    for (int e = 0; e < 8; ++e) p[e] = exp(lb[e] - mx);
    int i0 = 0;
    for (int e = 1; e < 8; ++e) if (p[e] > p[i0]) i0 = e;
    int i1 = (i0 == 0) ? 1 : 0;
    for (int e = 0; e < 8; ++e) if (e != i0 && p[e] > p[i1]) i1 = e;
    double den = p[i0] + p[i1];
    float o[8] = {0.f, 0.f, 0.f, 0.f, 0.f, 0.f, 0.f, 0.f};
    o[i0] = (float)(p[i0] / den);
    o[i1] = (float)(p[i1] / den);
#pragma unroll
    for (int e = 0; e < 8; ++e) gates[(size_t)t * 8 + e] = o[e];
  }
}

// ------------- ternary quant helper (f64 bins) -------------
__device__ __forceinline__ int qtern(float v, double winv) {
  double q = rint((double)v * winv);
  return (int)fmin(1.0, fmax(-1.0, q));
}
__device__ __forceinline__ unsigned pack4(int a, int b, int c, int d) {
  return (unsigned)(a & 255) | ((unsigned)(b & 255) << 8) |
         ((unsigned)(c & 255) << 16) | ((unsigned)(d & 255) << 24);
}

// ------------- weight quant + transpose: f32 [R][C] -> i8 W^T [C][R] -------------
__global__ __launch_bounds__(256) void k_wquant(
    const float* __restrict__ w1s, const float* __restrict__ w2s,
    const float* __restrict__ w1r, const float* __restrict__ w2r,
    const double* __restrict__ wscale,
    signed char* __restrict__ q1T, signed char* __restrict__ q2T) {
  __shared__ signed char tile[64 * 68];
  int bid = blockIdx.x;
  int m = bid >> 9, t = bid & 511;
  const float* src;
  signed char* dst;
  int ld, ldo, rt, ct;
  if (m < 2) {
    src = w1s + (size_t)m * DD * FF;
    dst = q1T + (size_t)m * FF * DD;
    ld = FF; ldo = DD; rt = t >> 5; ct = t & 31;
  } else if (m < 4) {
    src = w2s + (size_t)(m - 2) * FF * DD;
    dst = q2T + (size_t)(m - 2) * DD * FF;
    ld = DD; ldo = FF; rt = t >> 4; ct = t & 15;
  } else if (m < 12) {
    src = w1r + (size_t)(m - 4) * DD * FF;
    dst = q1T + (size_t)(m - 2) * FF * DD;
    ld = FF; ldo = DD; rt = t >> 5; ct = t & 31;
  } else {
    src = w2r + (size_t)(m - 12) * FF * DD;
    dst = q2T + (size_t)(m - 10) * DD * FF;
    ld = DD; ldo = FF; rt = t >> 4; ct = t & 15;
  }
  double winv = 1.0 / wscale[m];
  int row0 = rt * 64, col0 = ct * 64;
  int r = threadIdx.x >> 2, sc_ = (threadIdx.x & 3) * 16;
  const float* sp = src + (size_t)(row0 + r) * ld + col0 + sc_;
#pragma unroll
  for (int g = 0; g < 4; ++g) {
    float4 v = *(const float4*)(sp + g * 4);
    unsigned pk = pack4(qtern(v.x, winv), qtern(v.y, winv),
                        qtern(v.z, winv), qtern(v.w, winv));
    *(unsigned*)(tile + r * 68 + sc_ + g * 4) = pk;
  }
  __syncthreads();
  int c = threadIdx.x >> 2, sr = (threadIdx.x & 3) * 16;
  unsigned o[4];
#pragma unroll
  for (int g = 0; g < 4; ++g) {
    int j = sr + g * 4;
    o[g] = pack4(tile[(j + 0) * 68 + c], tile[(j + 1) * 68 + c],
                 tile[(j + 2) * 68 + c], tile[(j + 3) * 68 + c]);
  }
  int4 ov = make_int4((int)o[0], (int)o[1], (int)o[2], (int)o[3]);
  *(int4*)(dst + (size_t)(col0 + c) * ldo + row0 + sr) = ov;
}

// ------------- 64x64 MFMA tile (4 waves, 2x2 wave grid, 32x32 per wave) -------------
__device__ __forceinline__ void mfma_tile64(const signed char* As, const signed char* Bs,
                                            int lane, int wr, int wc, v4i acc[2][2]) {
  int kg = lane >> 4, rsel = lane & 15;
  v4i af[2], bf[2];
#pragma unroll
  for (int mi = 0; mi < 2; ++mi)
    af[mi] = *(const v4i*)(As + (wr * 32 + mi * 16 + rsel) * LDA + kg * 16);
#pragma unroll
  for (int ni = 0; ni < 2; ++ni)
    bf[ni] = *(const v4i*)(Bs + (wc * 32 + ni * 16 + rsel) * LDA + kg * 16);
#pragma unroll
  for (int mi = 0; mi < 2; ++mi)
#pragma unroll
    for (int ni = 0; ni < 2; ++ni)
      acc[mi][ni] = __builtin_amdgcn_mfma_i32_16x16x64_i8(af[mi], bf[ni], acc[mi][ni], 0, 0, 0);
}

// ------------- GEMM1 core: i32 tile of qh @ q1T^T for expert z -------------
__device__ __forceinline__ void gemm1_core(
    const signed char* __restrict__ qh, const signed char* __restrict__ qw,
    int row0, int col0, int tid, int lane, int wr, int wc, v4i acc[2][2]) {
  __shared__ signed char As[64 * LDA];
  __shared__ signed char Bs[64 * LDA];
  int arow = tid >> 2, aseg = (tid & 3) * 16;
  const signed char* ap = qh + (size_t)(row0 + arow) * DD + aseg;
  const signed char* bp = qw + (size_t)(col0 + arow) * DD + aseg;
  for (int k0 = 0; k0 < DD; k0 += 64) {
    __syncthreads();
    int4 va = *(const int4*)(ap + k0);
    int4 vb = *(const int4*)(bp + k0);
    *(int4*)(As + arow * LDA + aseg) = va;
    *(int4*)(Bs + arow * LDA + aseg) = vb;
    __syncthreads();
    mfma_tile64(As, Bs, lane, wr, wc, acc);
  }
}

// ------------- GEMM1 pass A: rowmax of |silu| only -------------
// grid (FF/64, TT/64, NEXPI)
__global__ __launch_bounds__(256) void k_gemm1max(
    const signed char* __restrict__ qh, const signed char* __restrict__ q1T,
    const double* __restrict__ wscale, const double* __restrict__ amax_clip,
    unsigned* __restrict__ rowmax) {
  int tid = threadIdx.x, lane = tid & 63, wid = tid >> 6;
  int wr = wid >> 1, wc = wid & 1;
  int row0 = blockIdx.y * 64, col0 = blockIdx.x * 64;
  int e = blockIdx.z;
  const signed char* qw = q1T + (size_t)e * FF * DD;
  double wsc = wscale[e < 2 ? e : e + 2];
  v4i zero = {0, 0, 0, 0};
  v4i acc[2][2] = {{zero, zero}, {zero, zero}};
  gemm1_core(qh, qw, row0, col0, tid, lane, wr, wc, acc);
  double csc = wsc * (1.0 / 127.0);
  unsigned* rme = rowmax + (size_t)e * TT;
#pragma unroll
  for (int mi = 0; mi < 2; ++mi) {
#pragma unroll
    for (int rg = 0; rg < 4; ++rg) {
      int tr = row0 + wr * 32 + mi * 16 + ((lane >> 4) << 2) + rg;
      float sA = (float)(amax_clip[tr] * csc);
      float mloc = 0.f;
#pragma unroll
      for (int ni = 0; ni < 2; ++ni) {
        float a = (float)acc[mi][ni][rg] * sA;
        float v = a / (1.f + expf(-a));
        mloc = fmaxf(mloc, fabsf(v));
      }
#pragma unroll
      for (int o = 1; o < 16; o <<= 1) mloc = fmaxf(mloc, __shfl_xor(mloc, o));
      if ((lane & 15) == 0) atomicMax(rme + tr, __float_as_uint(mloc));
    }
  }
}

// ------------- GEMM1 pass B: recompute, quantize silu -> qa int8 -------------
__global__ __launch_bounds__(256) void k_gemm1q(
    const signed char* __restrict__ qh, const signed char* __restrict__ q1T,
    const double* __restrict__ wscale, const double* __restrict__ amax_clip,
    const unsigned* __restrict__ rowmax, signed char* __restrict__ qa) {
  int tid = threadIdx.x, lane = tid & 63, wid = tid >> 6;
  int wr = wid >> 1, wc = wid & 1;
  int row0 = blockIdx.y * 64, col0 = blockIdx.x * 64;
  int e = blockIdx.z;
  const signed char* qw = q1T + (size_t)e * FF * DD;
  double wsc = wscale[e < 2 ? e : e + 2];
  v4i zero = {0, 0, 0, 0};
  v4i acc[2][2] = {{zero, zero}, {zero, zero}};
  gemm1_core(qh, qw, row0, col0, tid, lane, wr, wc, acc);
  double csc = wsc * (1.0 / 127.0);
  const unsigned* rme = rowmax + (size_t)e * TT;
  signed char* qae = qa + (size_t)e * TT * FF;
#pragma unroll
  for (int mi = 0; mi < 2; ++mi) {
#pragma unroll
    for (int rg = 0; rg < 4; ++rg) {
      int tr = row0 + wr * 32 + mi * 16 + ((lane >> 4) << 2) + rg;
      float sA = (float)(amax_clip[tr] * csc);
      float clip = fmaxf(__uint_as_float(rme[tr]), 1e-5f);
      float sAq = 127.f / clip;
#pragma unroll
      for (int ni = 0; ni < 2; ++ni) {
        int fc = col0 + wc * 32 + ni * 16 + (lane & 15);
        float a = (float)acc[mi][ni][rg] * sA;
        float v = a / (1.f + expf(-a));
        int q = (int)fminf(127.f, fmaxf(-128.f, rintf(v * sAq)));
        qae[(size_t)tr * FF + fc] = (signed char)q;
      }
    }
  }
}

// ------------- GEMM2: out = sum_e gate_e * ( qa_e @ q2T_e^T ) * scales -------------
// grid (DD/64, TT/64); loops all experts in-kernel, writes out once.
__global__ __launch_bounds__(256) void k_gemm2(
    const signed char* __restrict__ qa, const signed char* __restrict__ q2T,
    const double* __restrict__ wscale, const unsigned* __restrict__ rowmax,
    const float* __restrict__ gates, float* __restrict__ out) {
  __shared__ signed char As[64 * LDA];
  __shared__ signed char Bs[64 * LDA];
  int tid = threadIdx.x, lane = tid & 63, wid = tid >> 6;
  int wr = wid >> 1, wc = wid & 1;
  int row0 = blockIdx.y * 64, col0 = blockIdx.x * 64;
  int arow = tid >> 2, aseg = (tid & 3) * 16;
  float facc[2][2][4];
#pragma unroll
  for (int mi = 0; mi < 2; ++mi)
#pragma unroll
    for (int ni = 0; ni < 2; ++ni)
#pragma unroll
      for (int rg = 0; rg < 4; ++rg) facc[mi][ni][rg] = 0.f;

  for (int e = 0; e < NEXPI; ++e) {
    const signed char* ap = qa + (size_t)e * TT * FF + (size_t)(row0 + arow) * FF + aseg;
    const signed char* bp = q2T + (size_t)e * DD * FF + (size_t)(col0 + arow) * FF + aseg;
    double wsc = wscale[e < 2 ? e + 2 : e + 10];
    v4i zero = {0, 0, 0, 0};
    v4i acc[2][2] = {{zero, zero}, {zero, zero}};
    for (int k0 = 0; k0 < FF; k0 += 64) {
      __syncthreads();
      int4 va = *(const int4*)(ap + k0);
      int4 vb = *(const int4*)(bp + k0);
      *(int4*)(As + arow * LDA + aseg) = va;
      *(int4*)(Bs + arow * LDA + aseg) = vb;
      __syncthreads();
      mfma_tile64(As, Bs, lane, wr, wc, acc);
    }
    double csc = wsc * (1.0 / 127.0);
    const unsigned* rme = rowmax + (size_t)e * TT;
#pragma unroll
    for (int mi = 0; mi < 2; ++mi) {
#pragma unroll
      for (int rg = 0; rg < 4; ++rg) {
        int tr = row0 + wr * 32 + mi * 16 + ((lane >> 4) << 2) + rg;
        float clip2 = fmaxf(__uint_as_float(rme[tr]), 1e-5f);
        float g = (e < 2) ? 1.f : gates[(size_t)tr * 8 + (e - 2)];
        float sc = (float)((double)clip2 * csc) * g;
#pragma unroll
        for (int ni = 0; ni < 2; ++ni)
          facc[mi][ni][rg] += (float)acc[mi][ni][rg] * sc;
      }
    }
  }
#pragma unroll
  for (int mi = 0; mi < 2; ++mi) {
#pragma unroll
    for (int rg = 0; rg < 4; ++rg) {
      int tr = row0 + wr * 32 + mi * 16 + ((lane >> 4) << 2) + rg;
#pragma unroll
      for (int ni = 0; ni < 2; ++ni) {
        int dc = col0 + wc * 32 + ni * 16 + (lane & 15);
        out[(size_t)tr * DD + dc] = facc[mi][ni][rg];
      }
    }
  }
}

extern "C" void kernel_launch(void* const* d_in, const int* in_sizes, int n_in,
                              void* d_out, int out_size, void* d_ws, size_t ws_size,
                              hipStream_t stream) {
  const float* x    = (const float*)d_in[0];
  const float* rmsw = (const float*)d_in[1];
  const float* w1s  = (const float*)d_in[2];
  const float* w2s  = (const float*)d_in[3];
  const float* w1r  = (const float*)d_in[4];
  const float* w2r  = (const float*)d_in[5];
  const float* rw   = (const float*)d_in[6];
  float* out = (float*)d_out;

  char* ws = (char*)d_ws;
  // qh 2MB | amax_clip f64 16KB | part f64 20KB | wscale f64 | gates 64KB |
  // rowmax 80KB | hb 4MB | q1T 20MB | q2T 20MB | qa 40MB  (~86MB total)
  signed char* qh        = (signed char*)ws;
  double* amax_clip      = (double*)(ws + 0x200000);
  double* part           = (double*)(ws + 0x204000);
  double* wscale         = (double*)(ws + 0x209000);
  float* gates           = (float*)(ws + 0x20A000);
  unsigned* rowmax       = (unsigned*)(ws + 0x21A000);
  __hip_bfloat16* hb     = (__hip_bfloat16*)(ws + 0x22E000);
  signed char* q1T       = (signed char*)(ws + 0x62E000);
  signed char* q2T       = (signed char*)(ws + 0x1A2E000);
  signed char* qa        = (signed char*)(ws + 0x2E2E000);

  k_zero<<<(NEXPI * TT + 255) / 256, 256, 0, stream>>>(rowmax);
  k_rms_quant<<<TT, 256, 0, stream>>>(x, rmsw, qh, hb, amax_clip);
  k_wabs_part<<<20 * 128, 256, 0, stream>>>(w1s, w2s, w1r, w2r, part);
  k_wscale_final<<<20, 128, 0, stream>>>(part, wscale);
  k_router<<<TT, 64, 0, stream>>>(hb, rw, gates);
  k_wquant<<<20 * 512, 256, 0, stream>>>(w1s, w2s, w1r, w2r, wscale, q1T, q2T);

  dim3 g1(FF / 64, TT / 64, NEXPI);
  k_gemm1max<<<g1, 256, 0, stream>>>(qh, q1T, wscale, amax_clip, rowmax);
  k_gemm1q<<<g1, 256, 0, stream>>>(qh, q1T, wscale, amax_clip, rowmax, qa);
  dim3 g2(DD / 64, TT / 64);
  k_gemm2<<<g2, 256, 0, stream>>>(qa, q2T, wscale, rowmax, gates, out);
}

// Round 6
// 404.032 us; speedup vs baseline: 9.5440x; 1.1018x over previous
//
#include <hip/hip_runtime.h>
#include <hip/hip_bf16.h>

#define TT 2048
#define DD 1024
#define FF 2048
#define NEXPI 10   // 2 shared + 8 routed expert instances

typedef __attribute__((ext_vector_type(4))) int v4i;

__device__ __forceinline__ double wave_sum_d(double v) {
#pragma unroll
  for (int o = 32; o > 0; o >>= 1) v += __shfl_down(v, o);
  return v;
}
__device__ __forceinline__ double wave_max_d(double v) {
#pragma unroll
  for (int o = 32; o > 0; o >>= 1) v = fmax(v, __shfl_down(v, o));
  return v;
}

// async global->LDS, 16B per lane; lds must be wave-uniform, lane l lands at lds + l*16
__device__ __forceinline__ void gll16(const void* g, void* l) {
  __builtin_amdgcn_global_load_lds(
      (const __attribute__((address_space(1))) void*)g,
      (__attribute__((address_space(3))) void*)l, 16, 0, 0);
}

// ---------------- zero init (rowmax slots) ----------------
__global__ void k_zero(unsigned* __restrict__ rm) {
  int i = blockIdx.x * 256 + threadIdx.x;
  if (i < NEXPI * TT) rm[i] = 0u;
}

// ------------- rmsnorm + per-token absmax + int8 quant + bf16 h (f64 math) -------------
__global__ __launch_bounds__(256) void k_rms_quant(
    const float* __restrict__ x, const float* __restrict__ rw,
    signed char* __restrict__ qh, __hip_bfloat16* __restrict__ hb,
    double* __restrict__ amax_clip) {
  __shared__ double red[12];
  int t = blockIdx.x, tid = threadIdx.x;
  int lane = tid & 63, wid = tid >> 6;
  float4 xv = ((const float4*)(x + (size_t)t * DD))[tid];
  double x0 = xv.x, x1 = xv.y, x2 = xv.z, x3 = xv.w;
  double ss = x0 * x0 + x1 * x1 + x2 * x2 + x3 * x3;
  ss = wave_sum_d(ss);
  if (lane == 0) red[wid] = ss;
  __syncthreads();
  if (tid == 0) {
    double s = red[0] + red[1] + red[2] + red[3];
    red[8] = 1.0 / sqrt(s * (1.0 / DD) + 1e-6);
  }
  __syncthreads();
  double r = red[8];
  float4 wv = ((const float4*)rw)[tid];
  double h0 = x0 * r * (double)wv.x, h1 = x1 * r * (double)wv.y;
  double h2 = x2 * r * (double)wv.z, h3 = x3 * r * (double)wv.w;
  __hip_bfloat16* hp = hb + (size_t)t * DD + tid * 4;
  hp[0] = __float2bfloat16((float)h0); hp[1] = __float2bfloat16((float)h1);
  hp[2] = __float2bfloat16((float)h2); hp[3] = __float2bfloat16((float)h3);
  double am = fmax(fmax(fabs(h0), fabs(h1)), fmax(fabs(h2), fabs(h3)));
  am = wave_max_d(am);
  if (lane == 0) red[4 + wid] = am;
  __syncthreads();
  if (tid == 0) {
    double a = fmax(fmax(red[4], red[5]), fmax(red[6], red[7]));
    red[9] = fmax(a, 1e-5);
  }
  __syncthreads();
  double clipv = red[9];
  if (tid == 0) amax_clip[t] = clipv;
  double s = 127.0 / clipv;
  int q0 = (int)fmin(127.0, fmax(-128.0, rint(h0 * s)));
  int q1 = (int)fmin(127.0, fmax(-128.0, rint(h1 * s)));
  int q2 = (int)fmin(127.0, fmax(-128.0, rint(h2 * s)));
  int q3 = (int)fmin(127.0, fmax(-128.0, rint(h3 * s)));
  unsigned pw = (unsigned)(q0 & 255) | ((unsigned)(q1 & 255) << 8) |
                ((unsigned)(q2 & 255) << 16) | ((unsigned)(q3 & 255) << 24);
  *(unsigned*)(qh + (size_t)t * DD + tid * 4) = pw;
}

// ------------- weight absmean: f64 partial sums, 4-way ILP -------------
__global__ __launch_bounds__(256) void k_wabs_part(
    const float* __restrict__ w1s, const float* __restrict__ w2s,
    const float* __restrict__ w1r, const float* __restrict__ w2r,
    double* __restrict__ part) {
  __shared__ double red[4];
  int m = blockIdx.x >> 7, blk = blockIdx.x & 127;
  const float* base;
  if (m < 2)       base = w1s + (size_t)m * (DD * FF);
  else if (m < 4)  base = w2s + (size_t)(m - 2) * (DD * FF);
  else if (m < 12) base = w1r + (size_t)(m - 4) * (DD * FF);
  else             base = w2r + (size_t)(m - 12) * (DD * FF);
  const float4* p = (const float4*)(base + (size_t)blk * 16384);
  int tid = threadIdx.x;
  double s0 = 0.0, s1 = 0.0, s2 = 0.0, s3 = 0.0;
#pragma unroll
  for (int i = 0; i < 4; ++i) {
    float4 va = p[tid + (i * 4 + 0) * 256];
    float4 vb = p[tid + (i * 4 + 1) * 256];
    float4 vc = p[tid + (i * 4 + 2) * 256];
    float4 vd = p[tid + (i * 4 + 3) * 256];
    s0 += (double)fabsf(va.x) + (double)fabsf(va.y) + (double)fabsf(va.z) + (double)fabsf(va.w);
    s1 += (double)fabsf(vb.x) + (double)fabsf(vb.y) + (double)fabsf(vb.z) + (double)fabsf(vb.w);
    s2 += (double)fabsf(vc.x) + (double)fabsf(vc.y) + (double)fabsf(vc.z) + (double)fabsf(vc.w);
    s3 += (double)fabsf(vd.x) + (double)fabsf(vd.y) + (double)fabsf(vd.z) + (double)fabsf(vd.w);
  }
  double s = (s0 + s1) + (s2 + s3);
  s = wave_sum_d(s);
  int lane = tid & 63, wid = tid >> 6;
  if (lane == 0) red[wid] = s;
  __syncthreads();
  if (tid == 0) part[m * 128 + blk] = red[0] + red[1] + red[2] + red[3];
}

__global__ __launch_bounds__(128) void k_wscale_final(
    const double* __restrict__ part, double* __restrict__ wscale) {
  __shared__ double red[2];
  int m = blockIdx.x, tid = threadIdx.x;
  double v = part[m * 128 + tid];
  v = wave_sum_d(v);
  if ((tid & 63) == 0) red[tid >> 6] = v;
  __syncthreads();
  if (tid == 0) wscale[m] = (red[0] + red[1]) * (1.0 / 2097152.0) + 1e-8;
}

// ------------- router: bf16 products, f64 accum, bf16-rounded logits,
//               top-2 (lower-index tie-break), renorm -> dense gates -------------
__global__ __launch_bounds__(64) void k_router(
    const __hip_bfloat16* __restrict__ hb, const float* __restrict__ rw,
    float* __restrict__ gates) {
  int t = blockIdx.x, lane = threadIdx.x;
  double acc[8];
#pragma unroll
  for (int e = 0; e < 8; ++e) acc[e] = 0.0;
  const __hip_bfloat16* hp = hb + (size_t)t * DD;
  for (int d = lane; d < DD; d += 64) {
    double hv = (double)__bfloat162float(hp[d]);
#pragma unroll
    for (int e = 0; e < 8; ++e) {
      double wv = (double)__bfloat162float(__float2bfloat16(rw[e * DD + d]));
      acc[e] += hv * wv;
    }
  }
#pragma unroll
  for (int e = 0; e < 8; ++e) acc[e] = wave_sum_d(acc[e]);
  if (lane == 0) {
    double lb[8];
#pragma unroll
    for (int e = 0; e < 8; ++e)
      lb[e] = (double)__bfloat162float(__float2bfloat16((float)acc[e]));
    double mx = lb[0];
#pragma unroll
    for (int e = 1; e < 8; ++e) mx = fmax(mx, lb[e]);
    double p[8];
#pragma unroll
    for (int e = 0; e < 8; ++e) p[e] = exp(lb[e] - mx);
    int i0 = 0;
    for (int e = 1; e < 8; ++e) if (p[e] > p[i0]) i0 = e;
    int i1 = (i0 == 0) ? 1 : 0;
    for (int e = 0; e < 8; ++e) if (e != i0 && p[e] > p[i1]) i1 = e;
    double den = p[i0] + p[i1];
    float o[8] = {0.f, 0.f, 0.f, 0.f, 0.f, 0.f, 0.f, 0.f};
    o[i0] = (float)(p[i0] / den);
    o[i1] = (float)(p[i1] / den);
#pragma unroll
    for (int e = 0; e < 8; ++e) gates[(size_t)t * 8 + e] = o[e];
  }
}

// ------------- ternary quant helper (f64 bins) -------------
__device__ __forceinline__ int qtern(float v, double winv) {
  double q = rint((double)v * winv);
  return (int)fmin(1.0, fmax(-1.0, q));
}
__device__ __forceinline__ unsigned pack4(int a, int b, int c, int d) {
  return (unsigned)(a & 255) | ((unsigned)(b & 255) << 8) |
         ((unsigned)(c & 255) << 16) | ((unsigned)(d & 255) << 24);
}

// ------------- weight quant + transpose: f32 [R][C] -> i8 W^T [C][R] -------------
__global__ __launch_bounds__(256) void k_wquant(
    const float* __restrict__ w1s, const float* __restrict__ w2s,
    const float* __restrict__ w1r, const float* __restrict__ w2r,
    const double* __restrict__ wscale,
    signed char* __restrict__ q1T, signed char* __restrict__ q2T) {
  __shared__ signed char tile[64 * 68];
  int bid = blockIdx.x;
  int m = bid >> 9, t = bid & 511;
  const float* src;
  signed char* dst;
  int ld, ldo, rt, ct;
  if (m < 2) {
    src = w1s + (size_t)m * DD * FF;
    dst = q1T + (size_t)m * FF * DD;
    ld = FF; ldo = DD; rt = t >> 5; ct = t & 31;
  } else if (m < 4) {
    src = w2s + (size_t)(m - 2) * FF * DD;
    dst = q2T + (size_t)(m - 2) * DD * FF;
    ld = DD; ldo = FF; rt = t >> 4; ct = t & 15;
  } else if (m < 12) {
    src = w1r + (size_t)(m - 4) * DD * FF;
    dst = q1T + (size_t)(m - 2) * FF * DD;
    ld = FF; ldo = DD; rt = t >> 5; ct = t & 31;
  } else {
    src = w2r + (size_t)(m - 12) * FF * DD;
    dst = q2T + (size_t)(m - 10) * DD * FF;
    ld = DD; ldo = FF; rt = t >> 4; ct = t & 15;
  }
  double winv = 1.0 / wscale[m];
  int row0 = rt * 64, col0 = ct * 64;
  int r = threadIdx.x >> 2, sc_ = (threadIdx.x & 3) * 16;
  const float* sp = src + (size_t)(row0 + r) * ld + col0 + sc_;
#pragma unroll
  for (int g = 0; g < 4; ++g) {
    float4 v = *(const float4*)(sp + g * 4);
    unsigned pk = pack4(qtern(v.x, winv), qtern(v.y, winv),
                        qtern(v.z, winv), qtern(v.w, winv));
    *(unsigned*)(tile + r * 68 + sc_ + g * 4) = pk;
  }
  __syncthreads();
  int c = threadIdx.x >> 2, sr = (threadIdx.x & 3) * 16;
  unsigned o[4];
#pragma unroll
  for (int g = 0; g < 4; ++g) {
    int j = sr + g * 4;
    o[g] = pack4(tile[(j + 0) * 68 + c], tile[(j + 1) * 68 + c],
                 tile[(j + 2) * 68 + c], tile[(j + 3) * 68 + c]);
  }
  int4 ov = make_int4((int)o[0], (int)o[1], (int)o[2], (int)o[3]);
  *(int4*)(dst + (size_t)(col0 + c) * ldo + row0 + sr) = ov;
}

// ------------- stage a 128-row x 64-byte tile into linear LDS via global_load_lds ----
// src points at element (tile_row0, k0); rstride = global row stride in bytes
__device__ __forceinline__ void stage128(const signed char* src, int rstride,
                                         signed char* lds, int tid) {
  int w = tid >> 6, l = tid & 63;
  int sub = l >> 2, seg = (l & 3) * 16;
#pragma unroll
  for (int i = 0; i < 2; ++i) {
    int rbase = (w << 5) + (i << 4);
    gll16(src + (size_t)(rbase + sub) * rstride + seg, lds + rbase * 64);
  }
}

// ------------- 128x128 GEMM core: 4 waves (2x2), 4x4 16x16 frags each, BK=64 ----------
__device__ __forceinline__ void gemm_core_128(
    const signed char* __restrict__ a_src, const signed char* __restrict__ b_src,
    int K, signed char* As, signed char* Bs, int tid, int lane, int wr, int wc,
    v4i acc[4][4]) {
  int kg = (lane >> 4) * 16, rsel = lane & 15;
  for (int k0 = 0; k0 < K; k0 += 64) {
    __syncthreads();
    stage128(a_src + k0, K, As, tid);
    stage128(b_src + k0, K, Bs, tid);
    __syncthreads();   // compiler drains vmcnt(0) before s_barrier
    v4i af[4], bf[4];
#pragma unroll
    for (int mi = 0; mi < 4; ++mi)
      af[mi] = *(const v4i*)(As + (wr * 64 + mi * 16 + rsel) * 64 + kg);
#pragma unroll
    for (int ni = 0; ni < 4; ++ni)
      bf[ni] = *(const v4i*)(Bs + (wc * 64 + ni * 16 + rsel) * 64 + kg);
#pragma unroll
    for (int mi = 0; mi < 4; ++mi)
#pragma unroll
      for (int ni = 0; ni < 4; ++ni)
        acc[mi][ni] = __builtin_amdgcn_mfma_i32_16x16x64_i8(af[mi], bf[ni], acc[mi][ni], 0, 0, 0);
  }
}

// ------------- GEMM1 pass A: rowmax of |silu| only; grid (FF/128, TT/128, NEXPI) ------
__global__ __launch_bounds__(256) void k_gemm1max(
    const signed char* __restrict__ qh, const signed char* __restrict__ q1T,
    const double* __restrict__ wscale, const double* __restrict__ amax_clip,
    unsigned* __restrict__ rowmax) {
  __shared__ __align__(16) signed char As[128 * 64];
  __shared__ __align__(16) signed char Bs[128 * 64];
  int tid = threadIdx.x, lane = tid & 63, wid = tid >> 6;
  int wr = wid >> 1, wc = wid & 1;
  int row0 = blockIdx.y * 128, col0 = blockIdx.x * 128;
  int e = blockIdx.z;
  const signed char* qw = q1T + (size_t)e * FF * DD;
  double wsc = wscale[e < 2 ? e : e + 2];
  v4i zero = {0, 0, 0, 0};
  v4i acc[4][4];
#pragma unroll
  for (int i = 0; i < 4; ++i)
#pragma unroll
    for (int j = 0; j < 4; ++j) acc[i][j] = zero;
  gemm_core_128(qh + (size_t)row0 * DD, qw + (size_t)col0 * DD, DD,
                As, Bs, tid, lane, wr, wc, acc);
  double csc = wsc * (1.0 / 127.0);
  unsigned* rme = rowmax + (size_t)e * TT;
#pragma unroll
  for (int mi = 0; mi < 4; ++mi) {
#pragma unroll
    for (int rg = 0; rg < 4; ++rg) {
      int tr = row0 + wr * 64 + mi * 16 + ((lane >> 4) << 2) + rg;
      float sA = (float)(amax_clip[tr] * csc);
      float mloc = 0.f;
#pragma unroll
      for (int ni = 0; ni < 4; ++ni) {
        float a = (float)acc[mi][ni][rg] * sA;
        float v = a / (1.f + expf(-a));
        mloc = fmaxf(mloc, fabsf(v));
      }
#pragma unroll
      for (int o = 1; o < 16; o <<= 1) mloc = fmaxf(mloc, __shfl_xor(mloc, o));
      if ((lane & 15) == 0) atomicMax(rme + tr, __float_as_uint(mloc));
    }
  }
}

// ------------- GEMM1 pass B: recompute, quantize silu -> qa int8 ----------------------
__global__ __launch_bounds__(256) void k_gemm1q(
    const signed char* __restrict__ qh, const signed char* __restrict__ q1T,
    const double* __restrict__ wscale, const double* __restrict__ amax_clip,
    const unsigned* __restrict__ rowmax, signed char* __restrict__ qa) {
  __shared__ __align__(16) signed char As[128 * 64];
  __shared__ __align__(16) signed char Bs[128 * 64];
  int tid = threadIdx.x, lane = tid & 63, wid = tid >> 6;
  int wr = wid >> 1, wc = wid & 1;
  int row0 = blockIdx.y * 128, col0 = blockIdx.x * 128;
  int e = blockIdx.z;
  const signed char* qw = q1T + (size_t)e * FF * DD;
  double wsc = wscale[e < 2 ? e : e + 2];
  v4i zero = {0, 0, 0, 0};
  v4i acc[4][4];
#pragma unroll
  for (int i = 0; i < 4; ++i)
#pragma unroll
    for (int j = 0; j < 4; ++j) acc[i][j] = zero;
  gemm_core_128(qh + (size_t)row0 * DD, qw + (size_t)col0 * DD, DD,
                As, Bs, tid, lane, wr, wc, acc);
  double csc = wsc * (1.0 / 127.0);
  const unsigned* rme = rowmax + (size_t)e * TT;
  signed char* qae = qa + (size_t)e * TT * FF;
#pragma unroll
  for (int mi = 0; mi < 4; ++mi) {
#pragma unroll
    for (int rg = 0; rg < 4; ++rg) {
      int tr = row0 + wr * 64 + mi * 16 + ((lane >> 4) << 2) + rg;
      float sA = (float)(amax_clip[tr] * csc);
      float clip = fmaxf(__uint_as_float(rme[tr]), 1e-5f);
      float sAq = 127.f / clip;
#pragma unroll
      for (int ni = 0; ni < 4; ++ni) {
        int fc = col0 + wc * 64 + ni * 16 + (lane & 15);
        float a = (float)acc[mi][ni][rg] * sA;
        float v = a / (1.f + expf(-a));
        int q = (int)fminf(127.f, fmaxf(-128.f, rintf(v * sAq)));
        qae[(size_t)tr * FF + fc] = (signed char)q;
      }
    }
  }
}

// ------------- GEMM2: pbuf[z] = sum over expert pair {2z,2z+1}; grid (DD/128,TT/128,5) -
__global__ __launch_bounds__(256) void k_gemm2(
    const signed char* __restrict__ qa, const signed char* __restrict__ q2T,
    const double* __restrict__ wscale, const unsigned* __restrict__ rowmax,
    const float* __restrict__ gates, float* __restrict__ pbuf) {
  __shared__ __align__(16) signed char As[128 * 64];
  __shared__ __align__(16) signed char Bs[128 * 64];
  int tid = threadIdx.x, lane = tid & 63, wid = tid >> 6;
  int wr = wid >> 1, wc = wid & 1;
  int col0 = blockIdx.x * 128, row0 = blockIdx.y * 128;
  int z = blockIdx.z;
  float facc[4][4][4];
#pragma unroll
  for (int mi = 0; mi < 4; ++mi)
#pragma unroll
    for (int ni = 0; ni < 4; ++ni)
#pragma unroll
      for (int rg = 0; rg < 4; ++rg) facc[mi][ni][rg] = 0.f;

#pragma unroll
  for (int j = 0; j < 2; ++j) {
    int e = z * 2 + j;
    const signed char* ap = qa + (size_t)e * TT * FF + (size_t)row0 * FF;
    const signed char* bp = q2T + (size_t)e * DD * FF + (size_t)col0 * FF;
    v4i zero = {0, 0, 0, 0};
    v4i acc[4][4];
#pragma unroll
    for (int a = 0; a < 4; ++a)
#pragma unroll
      for (int b = 0; b < 4; ++b) acc[a][b] = zero;
    gemm_core_128(ap, bp, FF, As, Bs, tid, lane, wr, wc, acc);
    double wsc = wscale[e < 2 ? e + 2 : e + 10];
    double csc = wsc * (1.0 / 127.0);
    const unsigned* rme = rowmax + (size_t)e * TT;
#pragma unroll
    for (int mi = 0; mi < 4; ++mi) {
#pragma unroll
      for (int rg = 0; rg < 4; ++rg) {
        int tr = row0 + wr * 64 + mi * 16 + ((lane >> 4) << 2) + rg;
        float clip2 = fmaxf(__uint_as_float(rme[tr]), 1e-5f);
        float g = (e < 2) ? 1.f : gates[(size_t)tr * 8 + (e - 2)];
        float sc = (float)((double)clip2 * csc) * g;
#pragma unroll
        for (int ni = 0; ni < 4; ++ni)
          facc[mi][ni][rg] += (float)acc[mi][ni][rg] * sc;
      }
    }
  }
  float* pz = pbuf + (size_t)z * TT * DD;
#pragma unroll
  for (int mi = 0; mi < 4; ++mi) {
#pragma unroll
    for (int rg = 0; rg < 4; ++rg) {
      int tr = row0 + wr * 64 + mi * 16 + ((lane >> 4) << 2) + rg;
#pragma unroll
      for (int ni = 0; ni < 4; ++ni) {
        int dc = col0 + wc * 64 + ni * 16 + (lane & 15);
        pz[(size_t)tr * DD + dc] = facc[mi][ni][rg];
      }
    }
  }
}

// ------------- combine: out = sum_z pbuf[z] -------------
__global__ __launch_bounds__(256) void k_combine(
    const float* __restrict__ pbuf, float* __restrict__ out) {
  int i = blockIdx.x * 256 + threadIdx.x;  // float4 index
  float4 s = ((const float4*)pbuf)[i];
#pragma unroll
  for (int z = 1; z < 5; ++z) {
    float4 v = ((const float4*)(pbuf + (size_t)z * TT * DD))[i];
    s.x += v.x; s.y += v.y; s.z += v.z; s.w += v.w;
  }
  ((float4*)out)[i] = s;
}

extern "C" void kernel_launch(void* const* d_in, const int* in_sizes, int n_in,
                              void* d_out, int out_size, void* d_ws, size_t ws_size,
                              hipStream_t stream) {
  const float* x    = (const float*)d_in[0];
  const float* rmsw = (const float*)d_in[1];
  const float* w1s  = (const float*)d_in[2];
  const float* w2s  = (const float*)d_in[3];
  const float* w1r  = (const float*)d_in[4];
  const float* w2r  = (const float*)d_in[5];
  const float* rw   = (const float*)d_in[6];
  float* out = (float*)d_out;

  char* ws = (char*)d_ws;
  // small(256KB) | qh 2MB | hb 4MB | q1T 20MB | q2T 20MB | qa 40MB | pbuf 40MB  (~126.3MB)
  double* amax_clip      = (double*)(ws + 0x0000000);
  double* part           = (double*)(ws + 0x0004000);
  double* wscale         = (double*)(ws + 0x0009000);
  float* gates           = (float*)(ws + 0x000A000);
  unsigned* rowmax       = (unsigned*)(ws + 0x001A000);
  signed char* qh        = (signed char*)(ws + 0x0040000);
  __hip_bfloat16* hb     = (__hip_bfloat16*)(ws + 0x0240000);
  signed char* q1T       = (signed char*)(ws + 0x0640000);
  signed char* q2T       = (signed char*)(ws + 0x1A40000);
  signed char* qa        = (signed char*)(ws + 0x2E40000);
  float* pbuf            = (float*)(ws + 0x5640000);

  k_zero<<<(NEXPI * TT + 255) / 256, 256, 0, stream>>>(rowmax);
  k_rms_quant<<<TT, 256, 0, stream>>>(x, rmsw, qh, hb, amax_clip);
  k_wabs_part<<<20 * 128, 256, 0, stream>>>(w1s, w2s, w1r, w2r, part);
  k_wscale_final<<<20, 128, 0, stream>>>(part, wscale);
  k_router<<<TT, 64, 0, stream>>>(hb, rw, gates);
  k_wquant<<<20 * 512, 256, 0, stream>>>(w1s, w2s, w1r, w2r, wscale, q1T, q2T);

  dim3 g1(FF / 128, TT / 128, NEXPI);
  k_gemm1max<<<g1, 256, 0, stream>>>(qh, q1T, wscale, amax_clip, rowmax);
  k_gemm1q<<<g1, 256, 0, stream>>>(qh, q1T, wscale, amax_clip, rowmax, qa);
  dim3 g2(DD / 128, TT / 128, 5);
  k_gemm2<<<g2, 256, 0, stream>>>(qa, q2T, wscale, rowmax, gates, pbuf);
  k_combine<<<TT * DD / 4 / 256, 256, 0, stream>>>(pbuf, out);
}

// Round 7
// 358.134 us; speedup vs baseline: 10.7672x; 1.1282x over previous
//
#include <hip/hip_runtime.h>
#include <hip/hip_bf16.h>

#define TT 2048
#define DD 1024
#define FF 2048
#define NEXPI 10   // 2 shared + 8 routed expert instances

typedef __attribute__((ext_vector_type(4))) int v4i;

__device__ __forceinline__ double wave_sum_d(double v) {
#pragma unroll
  for (int o = 32; o > 0; o >>= 1) v += __shfl_down(v, o);
  return v;
}
__device__ __forceinline__ double wave_max_d(double v) {
#pragma unroll
  for (int o = 32; o > 0; o >>= 1) v = fmax(v, __shfl_down(v, o));
  return v;
}

// async global->LDS, 16B per lane; lds dest is wave-uniform base, lane l lands at +l*16
__device__ __forceinline__ void gll16(const void* g, void* l) {
  __builtin_amdgcn_global_load_lds(
      (const __attribute__((address_space(1))) void*)g,
      (__attribute__((address_space(3))) void*)l, 16, 0, 0);
}

// stage ROWS x 64B tile (i8, row stride K bytes in global) into linear LDS
template<int ROWS>
__device__ __forceinline__ void stage_rows(const signed char* src, int K,
                                           signed char* lds, int tid) {
  int w = tid >> 6, l = tid & 63;
  int sub = l >> 2, seg = (l & 3) * 16;
#pragma unroll
  for (int i = 0; i < ROWS / 64; ++i) {
    int rbase = w * (ROWS / 4) + i * 16;
    gll16(src + (size_t)(rbase + sub) * K + seg, lds + rbase * 64);
  }
}

// ---------------- zero init (rowmax slots) ----------------
__global__ void k_zero(unsigned* __restrict__ rm) {
  int i = blockIdx.x * 256 + threadIdx.x;
  if (i < NEXPI * TT) rm[i] = 0u;
}

// ------------- rmsnorm + per-token absmax + int8 quant + bf16 h (f64 math) -------------
__global__ __launch_bounds__(256) void k_rms_quant(
    const float* __restrict__ x, const float* __restrict__ rw,
    signed char* __restrict__ qh, __hip_bfloat16* __restrict__ hb,
    double* __restrict__ amax_clip) {
  __shared__ double red[12];
  int t = blockIdx.x, tid = threadIdx.x;
  int lane = tid & 63, wid = tid >> 6;
  float4 xv = ((const float4*)(x + (size_t)t * DD))[tid];
  double x0 = xv.x, x1 = xv.y, x2 = xv.z, x3 = xv.w;
  double ss = x0 * x0 + x1 * x1 + x2 * x2 + x3 * x3;
  ss = wave_sum_d(ss);
  if (lane == 0) red[wid] = ss;
  __syncthreads();
  if (tid == 0) {
    double s = red[0] + red[1] + red[2] + red[3];
    red[8] = 1.0 / sqrt(s * (1.0 / DD) + 1e-6);
  }
  __syncthreads();
  double r = red[8];
  float4 wv = ((const float4*)rw)[tid];
  double h0 = x0 * r * (double)wv.x, h1 = x1 * r * (double)wv.y;
  double h2 = x2 * r * (double)wv.z, h3 = x3 * r * (double)wv.w;
  __hip_bfloat16* hp = hb + (size_t)t * DD + tid * 4;
  hp[0] = __float2bfloat16((float)h0); hp[1] = __float2bfloat16((float)h1);
  hp[2] = __float2bfloat16((float)h2); hp[3] = __float2bfloat16((float)h3);
  double am = fmax(fmax(fabs(h0), fabs(h1)), fmax(fabs(h2), fabs(h3)));
  am = wave_max_d(am);
  if (lane == 0) red[4 + wid] = am;
  __syncthreads();
  if (tid == 0) {
    double a = fmax(fmax(red[4], red[5]), fmax(red[6], red[7]));
    red[9] = fmax(a, 1e-5);
  }
  __syncthreads();
  double clipv = red[9];
  if (tid == 0) amax_clip[t] = clipv;
  double s = 127.0 / clipv;
  int q0 = (int)fmin(127.0, fmax(-128.0, rint(h0 * s)));
  int q1 = (int)fmin(127.0, fmax(-128.0, rint(h1 * s)));
  int q2 = (int)fmin(127.0, fmax(-128.0, rint(h2 * s)));
  int q3 = (int)fmin(127.0, fmax(-128.0, rint(h3 * s)));
  unsigned pw = (unsigned)(q0 & 255) | ((unsigned)(q1 & 255) << 8) |
                ((unsigned)(q2 & 255) << 16) | ((unsigned)(q3 & 255) << 24);
  *(unsigned*)(qh + (size_t)t * DD + tid * 4) = pw;
}

// ------------- weight absmean: f64 partial sums, 20 matrices x 256 blocks -------------
__global__ __launch_bounds__(256) void k_wabs_part(
    const float* __restrict__ w1s, const float* __restrict__ w2s,
    const float* __restrict__ w1r, const float* __restrict__ w2r,
    double* __restrict__ part) {
  __shared__ double red[4];
  int m = blockIdx.x >> 8, blk = blockIdx.x & 255;
  const float* base;
  if (m < 2)       base = w1s + (size_t)m * (DD * FF);
  else if (m < 4)  base = w2s + (size_t)(m - 2) * (DD * FF);
  else if (m < 12) base = w1r + (size_t)(m - 4) * (DD * FF);
  else             base = w2r + (size_t)(m - 12) * (DD * FF);
  const float4* p = (const float4*)(base + (size_t)blk * 8192);
  int tid = threadIdx.x;
  double s0 = 0.0, s1 = 0.0, s2 = 0.0, s3 = 0.0;
#pragma unroll
  for (int i = 0; i < 2; ++i) {
    float4 va = p[tid + (i * 4 + 0) * 256];
    float4 vb = p[tid + (i * 4 + 1) * 256];
    float4 vc = p[tid + (i * 4 + 2) * 256];
    float4 vd = p[tid + (i * 4 + 3) * 256];
    s0 += (double)fabsf(va.x) + (double)fabsf(va.y) + (double)fabsf(va.z) + (double)fabsf(va.w);
    s1 += (double)fabsf(vb.x) + (double)fabsf(vb.y) + (double)fabsf(vb.z) + (double)fabsf(vb.w);
    s2 += (double)fabsf(vc.x) + (double)fabsf(vc.y) + (double)fabsf(vc.z) + (double)fabsf(vc.w);
    s3 += (double)fabsf(vd.x) + (double)fabsf(vd.y) + (double)fabsf(vd.z) + (double)fabsf(vd.w);
  }
  double s = (s0 + s1) + (s2 + s3);
  s = wave_sum_d(s);
  int lane = tid & 63, wid = tid >> 6;
  if (lane == 0) red[wid] = s;
  __syncthreads();
  if (tid == 0) part[m * 256 + blk] = red[0] + red[1] + red[2] + red[3];
}

__global__ __launch_bounds__(256) void k_wscale_final(
    const double* __restrict__ part, double* __restrict__ wscale) {
  __shared__ double red[4];
  int m = blockIdx.x, tid = threadIdx.x;
  double v = part[m * 256 + tid];
  v = wave_sum_d(v);
  if ((tid & 63) == 0) red[tid >> 6] = v;
  __syncthreads();
  if (tid == 0)
    wscale[m] = (red[0] + red[1] + red[2] + red[3]) * (1.0 / 2097152.0) + 1e-8;
}

// ------------- router: bf16 products, f64 accum, bf16-rounded logits,
//               top-2 (lower-index tie-break), renorm -> dense gates -------------
__global__ __launch_bounds__(64) void k_router(
    const __hip_bfloat16* __restrict__ hb, const float* __restrict__ rw,
    float* __restrict__ gates) {
  int t = blockIdx.x, lane = threadIdx.x;
  double acc[8];
#pragma unroll
  for (int e = 0; e < 8; ++e) acc[e] = 0.0;
  const __hip_bfloat16* hp = hb + (size_t)t * DD;
  for (int d = lane; d < DD; d += 64) {
    double hv = (double)__bfloat162float(hp[d]);
#pragma unroll
    for (int e = 0; e < 8; ++e) {
      double wv = (double)__bfloat162float(__float2bfloat16(rw[e * DD + d]));
      acc[e] += hv * wv;
    }
  }
#pragma unroll
  for (int e = 0; e < 8; ++e) acc[e] = wave_sum_d(acc[e]);
  if (lane == 0) {
    double lb[8];
#pragma unroll
    for (int e = 0; e < 8; ++e)
      lb[e] = (double)__bfloat162float(__float2bfloat16((float)acc[e]));
    double mx = lb[0];
#pragma unroll
    for (int e = 1; e < 8; ++e) mx = fmax(mx, lb[e]);
    double p[8];
#pragma unroll
    for (int e = 0; e < 8; ++e) p[e] = exp(lb[e] - mx);
    int i0 = 0;
    for (int e = 1; e < 8; ++e) if (p[e] > p[i0]) i0 = e;
    int i1 = (i0 == 0) ? 1 : 0;
    for (int e = 0; e < 8; ++e) if (e != i0 && p[e] > p[i1]) i1 = e;
    double den = p[i0] + p[i1];
    float o[8] = {0.f, 0.f, 0.f, 0.f, 0.f, 0.f, 0.f, 0.f};
    o[i0] = (float)(p[i0] / den);
    o[i1] = (float)(p[i1] / den);
#pragma unroll
    for (int e = 0; e < 8; ++e) gates[(size_t)t * 8 + e] = o[e];
  }
}

// ------------- ternary quant helper (f64 bins) -------------
__device__ __forceinline__ int qtern(float v, double winv) {
  double q = rint((double)v * winv);
  return (int)fmin(1.0, fmax(-1.0, q));
}
__device__ __forceinline__ unsigned pack4(int a, int b, int c, int d) {
  return (unsigned)(a & 255) | ((unsigned)(b & 255) << 8) |
         ((unsigned)(c & 255) << 16) | ((unsigned)(d & 255) << 24);
}

// ------------- weight quant + transpose: f32 [R][C] -> i8 W^T [C][R] -------------
__global__ __launch_bounds__(256) void k_wquant(
    const float* __restrict__ w1s, const float* __restrict__ w2s,
    const float* __restrict__ w1r, const float* __restrict__ w2r,
    const double* __restrict__ wscale,
    signed char* __restrict__ q1T, signed char* __restrict__ q2T) {
  __shared__ signed char tile[64 * 68];
  int bid = blockIdx.x;
  int m = bid >> 9, t = bid & 511;
  const float* src;
  signed char* dst;
  int ld, ldo, rt, ct;
  if (m < 2) {
    src = w1s + (size_t)m * DD * FF;
    dst = q1T + (size_t)m * FF * DD;
    ld = FF; ldo = DD; rt = t >> 5; ct = t & 31;
  } else if (m < 4) {
    src = w2s + (size_t)(m - 2) * FF * DD;
    dst = q2T + (size_t)(m - 2) * DD * FF;
    ld = DD; ldo = FF; rt = t >> 4; ct = t & 15;
  } else if (m < 12) {
    src = w1r + (size_t)(m - 4) * DD * FF;
    dst = q1T + (size_t)(m - 2) * FF * DD;
    ld = FF; ldo = DD; rt = t >> 5; ct = t & 31;
  } else {
    src = w2r + (size_t)(m - 12) * FF * DD;
    dst = q2T + (size_t)(m - 10) * DD * FF;
    ld = DD; ldo = FF; rt = t >> 4; ct = t & 15;
  }
  double winv = 1.0 / wscale[m];
  int row0 = rt * 64, col0 = ct * 64;
  int r = threadIdx.x >> 2, sc_ = (threadIdx.x & 3) * 16;
  const float* sp = src + (size_t)(row0 + r) * ld + col0 + sc_;
#pragma unroll
  for (int g = 0; g < 4; ++g) {
    float4 v = *(const float4*)(sp + g * 4);
    unsigned pk = pack4(qtern(v.x, winv), qtern(v.y, winv),
                        qtern(v.z, winv), qtern(v.w, winv));
    *(unsigned*)(tile + r * 68 + sc_ + g * 4) = pk;
  }
  __syncthreads();
  int c = threadIdx.x >> 2, sr = (threadIdx.x & 3) * 16;
  unsigned o[4];
#pragma unroll
  for (int g = 0; g < 4; ++g) {
    int j = sr + g * 4;
    o[g] = pack4(tile[(j + 0) * 68 + c], tile[(j + 1) * 68 + c],
                 tile[(j + 2) * 68 + c], tile[(j + 3) * 68 + c]);
  }
  int4 ov = make_int4((int)o[0], (int)o[1], (int)o[2], (int)o[3]);
  *(int4*)(dst + (size_t)(col0 + c) * ldo + row0 + sr) = ov;
}

// ------------- scale precompute -------------
// srow1[e][t] = amax_clip[t] * wscale1[e] / 127   (gemm1 silu input scale)
__global__ __launch_bounds__(256) void k_scales1(
    const double* __restrict__ amax_clip, const double* __restrict__ wscale,
    float* __restrict__ srow1) {
  int i = blockIdx.x * 256 + threadIdx.x;   // i = e*TT + t
  if (i >= NEXPI * TT) return;
  int e = i >> 11, t = i & (TT - 1);
  double wsc = wscale[e < 2 ? e : e + 2];
  double csc = wsc * (1.0 / 127.0);
  srow1[i] = (float)(amax_clip[t] * csc);
}

// s1q[e][t] = 127/clip ; sg2[e][t] = float(clip * wscale2[e]/127) * gate
__global__ __launch_bounds__(256) void k_scales2(
    const unsigned* __restrict__ rowmax, const double* __restrict__ wscale,
    const float* __restrict__ gates, float* __restrict__ s1q,
    float* __restrict__ sg2) {
  int i = blockIdx.x * 256 + threadIdx.x;
  if (i >= NEXPI * TT) return;
  int e = i >> 11, t = i & (TT - 1);
  float clip = fmaxf(__uint_as_float(rowmax[i]), 1e-5f);
  s1q[i] = 127.f / clip;
  double csc = wscale[e < 2 ? e + 2 : e + 10] * (1.0 / 127.0);
  float g = (e < 2) ? 1.f : gates[(size_t)t * 8 + (e - 2)];
  sg2[i] = (float)((double)clip * csc) * g;
}

// ------------- 128x128 GEMM core, issue-early double-buffered -------------
// As/Bs: 2 x 8192 B each
__device__ __forceinline__ void core128(
    const signed char* __restrict__ a_src, const signed char* __restrict__ b_src,
    int K, signed char* As, signed char* Bs, int tid, int lane, int wr, int wc,
    v4i acc[4][4]) {
  int kg = (lane >> 4) * 16, rsel = lane & 15;
  stage_rows<128>(a_src, K, As, tid);
  stage_rows<128>(b_src, K, Bs, tid);
  __syncthreads();
  int nk = K >> 6, cur = 0;
  for (int t = 0; t < nk; ++t) {
    int nxt = cur ^ 1;
    if (t + 1 < nk) {
      stage_rows<128>(a_src + (t + 1) * 64, K, As + nxt * 8192, tid);
      stage_rows<128>(b_src + (t + 1) * 64, K, Bs + nxt * 8192, tid);
    }
    const signed char* Ac = As + cur * 8192;
    const signed char* Bc = Bs + cur * 8192;
    v4i af[4], bf[4];
#pragma unroll
    for (int mi = 0; mi < 4; ++mi)
      af[mi] = *(const v4i*)(Ac + (wr * 64 + mi * 16 + rsel) * 64 + kg);
#pragma unroll
    for (int ni = 0; ni < 4; ++ni)
      bf[ni] = *(const v4i*)(Bc + (wc * 64 + ni * 16 + rsel) * 64 + kg);
#pragma unroll
    for (int mi = 0; mi < 4; ++mi)
#pragma unroll
      for (int ni = 0; ni < 4; ++ni)
        acc[mi][ni] = __builtin_amdgcn_mfma_i32_16x16x64_i8(af[mi], bf[ni], acc[mi][ni], 0, 0, 0);
    __syncthreads();
    cur = nxt;
  }
}

// ------------- 64x128 GEMM core (A 64 rows, B 128 rows), double-buffered -------------
// As: 2 x 4096 B ; Bs: 2 x 8192 B
__device__ __forceinline__ void core64x128(
    const signed char* __restrict__ a_src, const signed char* __restrict__ b_src,
    int K, signed char* As, signed char* Bs, int tid, int lane, int wr, int wc,
    v4i acc[2][4]) {
  int kg = (lane >> 4) * 16, rsel = lane & 15;
  stage_rows<64>(a_src, K, As, tid);
  stage_rows<128>(b_src, K, Bs, tid);
  __syncthreads();
  int nk = K >> 6, cur = 0;
  for (int t = 0; t < nk; ++t) {
    int nxt = cur ^ 1;
    if (t + 1 < nk) {
      stage_rows<64>(a_src + (t + 1) * 64, K, As + nxt * 4096, tid);
      stage_rows<128>(b_src + (t + 1) * 64, K, Bs + nxt * 8192, tid);
    }
    const signed char* Ac = As + cur * 4096;
    const signed char* Bc = Bs + cur * 8192;
    v4i af[2], bf[4];
#pragma unroll
    for (int mi = 0; mi < 2; ++mi)
      af[mi] = *(const v4i*)(Ac + (wr * 32 + mi * 16 + rsel) * 64 + kg);
#pragma unroll
    for (int ni = 0; ni < 4; ++ni)
      bf[ni] = *(const v4i*)(Bc + (wc * 64 + ni * 16 + rsel) * 64 + kg);
#pragma unroll
    for (int mi = 0; mi < 2; ++mi)
#pragma unroll
      for (int ni = 0; ni < 4; ++ni)
        acc[mi][ni] = __builtin_amdgcn_mfma_i32_16x16x64_i8(af[mi], bf[ni], acc[mi][ni], 0, 0, 0);
    __syncthreads();
    cur = nxt;
  }
}

// ------------- GEMM1 pass A: rowmax of |silu|; logical grid (16,16,10), swizzled ------
__global__ __launch_bounds__(256) void k_gemm1max(
    const signed char* __restrict__ qh, const signed char* __restrict__ q1T,
    const float* __restrict__ srow1, unsigned* __restrict__ rowmax) {
  __shared__ __align__(16) signed char As[2 * 8192];
  __shared__ __align__(16) signed char Bs[2 * 8192];
  int lid = blockIdx.x + 16 * blockIdx.y + 256 * blockIdx.z;
  int nid = (lid & 7) * 320 + (lid >> 3);
  int e = nid >> 8, rr = nid & 255;
  int row0 = (rr >> 4) * 128, col0 = (rr & 15) * 128;
  int tid = threadIdx.x, lane = tid & 63, wid = tid >> 6;
  int wr = wid >> 1, wc = wid & 1;
  const signed char* qw = q1T + (size_t)e * FF * DD;
  v4i zero = {0, 0, 0, 0};
  v4i acc[4][4];
#pragma unroll
  for (int i = 0; i < 4; ++i)
#pragma unroll
    for (int j = 0; j < 4; ++j) acc[i][j] = zero;
  core128(qh + (size_t)row0 * DD, qw + (size_t)col0 * DD, DD,
          As, Bs, tid, lane, wr, wc, acc);
  const float* sr = srow1 + (size_t)e * TT;
  unsigned* rme = rowmax + (size_t)e * TT;
#pragma unroll
  for (int mi = 0; mi < 4; ++mi) {
#pragma unroll
    for (int rg = 0; rg < 4; ++rg) {
      int tr = row0 + wr * 64 + mi * 16 + ((lane >> 4) << 2) + rg;
      float sA = sr[tr];
      float mloc = 0.f;
#pragma unroll
      for (int ni = 0; ni < 4; ++ni) {
        float a = (float)acc[mi][ni][rg] * sA;
        float v = a / (1.f + expf(-a));
        mloc = fmaxf(mloc, fabsf(v));
      }
#pragma unroll
      for (int o = 1; o < 16; o <<= 1) mloc = fmaxf(mloc, __shfl_xor(mloc, o));
      if ((lane & 15) == 0) atomicMax(rme + tr, __float_as_uint(mloc));
    }
  }
}

// ------------- GEMM1 pass B: recompute, quantize silu -> qa int8 ----------------------
__global__ __launch_bounds__(256) void k_gemm1q(
    const signed char* __restrict__ qh, const signed char* __restrict__ q1T,
    const float* __restrict__ srow1, const float* __restrict__ s1q,
    signed char* __restrict__ qa) {
  __shared__ __align__(16) signed char As[2 * 8192];
  __shared__ __align__(16) signed char Bs[2 * 8192];
  int lid = blockIdx.x + 16 * blockIdx.y + 256 * blockIdx.z;
  int nid = (lid & 7) * 320 + (lid >> 3);
  int e = nid >> 8, rr = nid & 255;
  int row0 = (rr >> 4) * 128, col0 = (rr & 15) * 128;
  int tid = threadIdx.x, lane = tid & 63, wid = tid >> 6;
  int wr = wid >> 1, wc = wid & 1;
  const signed char* qw = q1T + (size_t)e * FF * DD;
  v4i zero = {0, 0, 0, 0};
  v4i acc[4][4];
#pragma unroll
  for (int i = 0; i < 4; ++i)
#pragma unroll
    for (int j = 0; j < 4; ++j) acc[i][j] = zero;
  core128(qh + (size_t)row0 * DD, qw + (size_t)col0 * DD, DD,
          As, Bs, tid, lane, wr, wc, acc);
  const float* sr = srow1 + (size_t)e * TT;
  const float* sq = s1q + (size_t)e * TT;
  signed char* qae = qa + (size_t)e * TT * FF;
#pragma unroll
  for (int mi = 0; mi < 4; ++mi) {
#pragma unroll
    for (int rg = 0; rg < 4; ++rg) {
      int tr = row0 + wr * 64 + mi * 16 + ((lane >> 4) << 2) + rg;
      float sA = sr[tr];
      float sAq = sq[tr];
#pragma unroll
      for (int ni = 0; ni < 4; ++ni) {
        int fc = col0 + wc * 64 + ni * 16 + (lane & 15);
        float a = (float)acc[mi][ni][rg] * sA;
        float v = a / (1.f + expf(-a));
        int q = (int)fminf(127.f, fmaxf(-128.f, rintf(v * sAq)));
        qae[(size_t)tr * FF + fc] = (signed char)q;
      }
    }
  }
}

// ------------- GEMM2: pbuf[z] = sum over expert pair {2z,2z+1} --------------------
// logical grid (8,32,5), 64x128 tiles, swizzled
__global__ __launch_bounds__(256) void k_gemm2(
    const signed char* __restrict__ qa, const signed char* __restrict__ q2T,
    const float* __restrict__ sg2, float* __restrict__ pbuf) {
  __shared__ __align__(16) signed char As[2 * 4096];
  __shared__ __align__(16) signed char Bs[2 * 8192];
  int lid = blockIdx.x + 8 * blockIdx.y + 256 * blockIdx.z;
  int nid = (lid & 7) * 160 + (lid >> 3);
  int z = nid >> 8, rr = nid & 255;
  int row0 = (rr >> 3) * 64, col0 = (rr & 7) * 128;
  int tid = threadIdx.x, lane = tid & 63, wid = tid >> 6;
  int wr = wid >> 1, wc = wid & 1;
  float facc[2][4][4];
#pragma unroll
  for (int mi = 0; mi < 2; ++mi)
#pragma unroll
    for (int ni = 0; ni < 4; ++ni)
#pragma unroll
      for (int rg = 0; rg < 4; ++rg) facc[mi][ni][rg] = 0.f;

#pragma unroll
  for (int j = 0; j < 2; ++j) {
    int e = z * 2 + j;
    const signed char* ap = qa + (size_t)e * TT * FF + (size_t)row0 * FF;
    const signed char* bp = q2T + (size_t)e * DD * FF + (size_t)col0 * FF;
    v4i zero = {0, 0, 0, 0};
    v4i acc[2][4];
#pragma unroll
    for (int a = 0; a < 2; ++a)
#pragma unroll
      for (int b = 0; b < 4; ++b) acc[a][b] = zero;
    core64x128(ap, bp, FF, As, Bs, tid, lane, wr, wc, acc);
    const float* sge = sg2 + (size_t)e * TT;
#pragma unroll
    for (int mi = 0; mi < 2; ++mi) {
#pragma unroll
      for (int rg = 0; rg < 4; ++rg) {
        int tr = row0 + wr * 32 + mi * 16 + ((lane >> 4) << 2) + rg;
        float sc = sge[tr];
#pragma unroll
        for (int ni = 0; ni < 4; ++ni)
          facc[mi][ni][rg] += (float)acc[mi][ni][rg] * sc;
      }
    }
    __syncthreads();
  }
  float* pz = pbuf + (size_t)z * TT * DD;
#pragma unroll
  for (int mi = 0; mi < 2; ++mi) {
#pragma unroll
    for (int rg = 0; rg < 4; ++rg) {
      int tr = row0 + wr * 32 + mi * 16 + ((lane >> 4) << 2) + rg;
#pragma unroll
      for (int ni = 0; ni < 4; ++ni) {
        int dc = col0 + wc * 64 + ni * 16 + (lane & 15);
        pz[(size_t)tr * DD + dc] = facc[mi][ni][rg];
      }
    }
  }
}

// ------------- combine: out = sum_z pbuf[z] -------------
__global__ __launch_bounds__(256) void k_combine(
    const float* __restrict__ pbuf, float* __restrict__ out) {
  int i = blockIdx.x * 256 + threadIdx.x;  // float4 index
  float4 s = ((const float4*)pbuf)[i];
#pragma unroll
  for (int z = 1; z < 5; ++z) {
    float4 v = ((const float4*)(pbuf + (size_t)z * TT * DD))[i];
    s.x += v.x; s.y += v.y; s.z += v.z; s.w += v.w;
  }
  ((float4*)out)[i] = s;
}

extern "C" void kernel_launch(void* const* d_in, const int* in_sizes, int n_in,
                              void* d_out, int out_size, void* d_ws, size_t ws_size,
                              hipStream_t stream) {
  const float* x    = (const float*)d_in[0];
  const float* rmsw = (const float*)d_in[1];
  const float* w1s  = (const float*)d_in[2];
  const float* w2s  = (const float*)d_in[3];
  const float* w1r  = (const float*)d_in[4];
  const float* w2r  = (const float*)d_in[5];
  const float* rw   = (const float*)d_in[6];
  float* out = (float*)d_out;

  char* ws = (char*)d_ws;
  double* amax_clip      = (double*)(ws + 0x0000000);   // 16KB
  double* part           = (double*)(ws + 0x0004000);   // 40KB
  double* wscale         = (double*)(ws + 0x000E000);   // 160B
  float* gates           = (float*)(ws + 0x0010000);    // 64KB
  unsigned* rowmax       = (unsigned*)(ws + 0x0020000); // 80KB
  float* srow1           = (float*)(ws + 0x0034000);    // 80KB
  float* s1q             = (float*)(ws + 0x0048000);    // 80KB
  float* sg2             = (float*)(ws + 0x005C000);    // 80KB
  signed char* qh        = (signed char*)(ws + 0x0080000);   // 2MB
  __hip_bfloat16* hb     = (__hip_bfloat16*)(ws + 0x0280000); // 4MB
  signed char* q1T       = (signed char*)(ws + 0x0680000);   // 20MB
  signed char* q2T       = (signed char*)(ws + 0x1A80000);   // 20MB
  signed char* qa        = (signed char*)(ws + 0x2E80000);   // 40MB
  float* pbuf            = (float*)(ws + 0x5680000);         // 40MB

  k_zero<<<(NEXPI * TT + 255) / 256, 256, 0, stream>>>(rowmax);
  k_rms_quant<<<TT, 256, 0, stream>>>(x, rmsw, qh, hb, amax_clip);
  k_wabs_part<<<20 * 256, 256, 0, stream>>>(w1s, w2s, w1r, w2r, part);
  k_wscale_final<<<20, 256, 0, stream>>>(part, wscale);
  k_router<<<TT, 64, 0, stream>>>(hb, rw, gates);
  k_wquant<<<20 * 512, 256, 0, stream>>>(w1s, w2s, w1r, w2r, wscale, q1T, q2T);
  k_scales1<<<(NEXPI * TT + 255) / 256, 256, 0, stream>>>(amax_clip, wscale, srow1);

  dim3 g1(16, 16, NEXPI);
  k_gemm1max<<<g1, 256, 0, stream>>>(qh, q1T, srow1, rowmax);
  k_scales2<<<(NEXPI * TT + 255) / 256, 256, 0, stream>>>(rowmax, wscale, gates, s1q, sg2);
  k_gemm1q<<<g1, 256, 0, stream>>>(qh, q1T, srow1, s1q, qa);
  dim3 g2(8, 32, 5);
  k_gemm2<<<g2, 256, 0, stream>>>(qa, q2T, sg2, pbuf);
  k_combine<<<TT * DD / 4 / 256, 256, 0, stream>>>(pbuf, out);
}